// Round 16
// baseline (305.629 us; speedup 1.0000x reference)
//
#include <hip/hip_runtime.h>
#include <math.h>

#define B_ 16
#define T_ 1024
#define D_ 96
#define L_ 6
#define NH_ 6
#define HS_ 16
#define FF_ 384

typedef _Float16 h4 __attribute__((ext_vector_type(4)));
typedef __fp16 g2 __attribute__((ext_vector_type(2)));
typedef __fp16 g4 __attribute__((ext_vector_type(4)));
typedef float f4 __attribute__((ext_vector_type(4)));

#define MFMA16 __builtin_amdgcn_mfma_f32_16x16x16f16

// packed f16 W^T buffer segment offsets (in halves)
#define OFF_GO   0
#define OFF_QKV  9216
#define OFF_PROJ 175104
#define OFF_FF1  230400
#define OFF_FF2  451584
#define OFF_ACT  672768
#define PACK_TOTAL 674304

// Q weights pre-scaled by 1/sqrt(16) * log2(e) so attn uses exp2 directly.
#define QSCALE 0.3606737602222409f

static __device__ __forceinline__ h4 pk4(const float* p) {
  g2 lo = __builtin_amdgcn_cvt_pkrtz(p[0], p[1]);
  g2 hi = __builtin_amdgcn_cvt_pkrtz(p[2], p[3]);
  g4 r4 = __builtin_shufflevector(lo, hi, 0, 1, 2, 3);
  return __builtin_bit_cast(h4, r4);
}

// ---------- pack all weights -> f16 W^T [N][K] ----------
__global__ __launch_bounds__(256) void pack_all_kernel(
    const float* __restrict__ w_go, const float* __restrict__ wq,
    const float* __restrict__ wk, const float* __restrict__ wv,
    const float* __restrict__ w_proj, const float* __restrict__ w_ff1,
    const float* __restrict__ w_ff2, const float* __restrict__ w_act,
    _Float16* __restrict__ P) {
  int i = blockIdx.x * 256 + threadIdx.x;
  if (i >= PACK_TOTAL) return;
  float v;
  if (i < OFF_QKV) {                       // w_go [96k][96n] -> [n][k]
    int o = i, n = o / 96, k = o % 96;
    v = w_go[k * 96 + n];
  } else if (i < OFF_PROJ) {               // wq/wk/wv -> [l][c=288][d=96]
    int o = i - OFF_QKV;
    int l = o / 27648, r = o % 27648, c = r / 96, d = r % 96;
    int which = c / 96;
    int hc = c % 96, h = hc >> 4, jx = hc & 15;
    const float* s = (which == 0) ? wq : (which == 1 ? wk : wv);
    v = s[((l * NH_ + h) * 96 + d) * 16 + jx];
    if (which == 0) v *= QSCALE;
  } else if (i < OFF_FF1) {                // w_proj [l][96k][96n] -> [l][n][k]
    int o = i - OFF_PROJ;
    int l = o / 9216, r = o % 9216, n = r / 96, k = r % 96;
    v = w_proj[l * 9216 + k * 96 + n];
  } else if (i < OFF_FF2) {                // w_ff1 [l][96k][384n] -> [l][n][k]
    int o = i - OFF_FF1;
    int l = o / 36864, r = o % 36864, n = r / 96, k = r % 96;
    v = w_ff1[l * 36864 + k * 384 + n];
  } else if (i < OFF_ACT) {                // w_ff2 [l][384k][96n] -> [l][n][k]
    int o = i - OFF_FF2;
    int l = o / 36864, r = o % 36864, n = r / 384, k = r % 384;
    v = w_ff2[l * 36864 + k * 96 + n];
  } else {                                 // w_act [96k][16n] -> [n][k]
    int o = i - OFF_ACT;
    int n = o / 96, k = o % 96;
    v = w_act[k * 16 + n];
  }
  P[i] = (_Float16)v;
}

// ---------- stage kernel: 6 waves x 2 token-groups (32 tokens) ----------
// Same wave layout as the r9/r15 4-group stage (each wave loads each weight
// once: wf 6, ff1 24, w2f 24, tail 24) but 2 groups -> LDS ~32KB so TWO
// blocks co-reside per CU (grid 512) = 3 waves/SIMD (was 1.5).
template <bool EMBED, bool HEAD>
__global__ __attribute__((amdgpu_flat_work_group_size(384, 384)))
__attribute__((amdgpu_waves_per_eu(3, 3)))
void stage_kernel(
    const float* __restrict__ goals, const float* __restrict__ obss,
    const float* __restrict__ pos, const float* __restrict__ b_go,
    const _Float16* __restrict__ obh, const _Float16* __restrict__ Wp,
    const float* __restrict__ bp, float* __restrict__ x,
    const _Float16* __restrict__ W1, const float* __restrict__ b1,
    const _Float16* __restrict__ W2, const float* __restrict__ b2,
    const float* __restrict__ ln2g, const float* __restrict__ ln2b,
    const float* __restrict__ lntg, const float* __restrict__ lntb,
    const _Float16* __restrict__ Wtail, const float* __restrict__ btail,
    _Float16* __restrict__ qh, _Float16* __restrict__ kh,
    _Float16* __restrict__ vt, float* __restrict__ out) {
  __shared__ float smemf[8064];  // 32256 B -> 2 blocks/CU
#define XSH(g, row, c) ((_Float16*)smemf + (size_t)(g) * 1920 + (row) * 20 + (c))
#define HSH(g, f, r, c) ((_Float16*)smemf + (size_t)(g) * 7680 + ((f) * 16 + (r)) * 20 + (c))
#define LNS(g, w, r, i) smemf[7680 + (((g) * 6 + (w)) * 16 + (r)) * 2 + (i)]
  const int tid = threadIdx.x;
  const int wave = tid >> 6, lane = tid & 63;
  const int lr = lane & 15, lg = lane >> 4;
  const int row0 = blockIdx.x * 32;
  const int bidx = row0 >> 10;
  const int cfo = wave;  // owned col-frag 0..5
  const f4 zero4 = {0.f, 0.f, 0.f, 0.f};
  int tok[2], tt[2];
#pragma unroll
  for (int g = 0; g < 2; ++g) { tok[g] = row0 + g * 16 + lr; tt[g] = tok[g] & 1023; }

  f4 xc[2], x1[2];

  if constexpr (EMBED) {
    h4 ef[2][6];
#pragma unroll
    for (int st = 0; st < 2; ++st) {
      f4 s4 = *(const f4*)(goals + bidx * 32 + st * 16 + lg * 4);
      h4 e = (h4){(_Float16)s4[0], (_Float16)s4[1], (_Float16)s4[2], (_Float16)s4[3]};
#pragma unroll
      for (int g = 0; g < 2; ++g) ef[g][st] = e;
    }
#pragma unroll
    for (int g = 0; g < 2; ++g)
#pragma unroll
      for (int st = 2; st < 6; ++st) {
        f4 s4 = *(const f4*)(obss + (size_t)(bidx * 1024 + tt[g]) * 64 +
                             (st - 2) * 16 + lg * 4);
        ef[g][st] = (h4){(_Float16)s4[0], (_Float16)s4[1], (_Float16)s4[2], (_Float16)s4[3]};
      }
    h4 wf[6];
    const _Float16* wrow = Wp + (size_t)(cfo * 16 + lr) * 96 + lg * 4;
#pragma unroll
    for (int st = 0; st < 6; ++st) wf[st] = *(const h4*)(wrow + st * 16);
    f4 bb = *(const f4*)(b_go + cfo * 16 + lg * 4);
#pragma unroll
    for (int g = 0; g < 2; ++g) {
      f4 a = zero4;
#pragma unroll
      for (int st = 0; st < 6; ++st) a = MFMA16(wf[st], ef[g][st], a, 0, 0, 0);
      f4 pp = *(const f4*)(pos + (size_t)tt[g] * 96 + cfo * 16 + lg * 4);
#pragma unroll
      for (int j = 0; j < 4; ++j) xc[g][j] = a[j] + bb[j] + pp[j];
      *(f4*)(x + (size_t)tok[g] * 96 + cfo * 16 + lg * 4) = xc[g];
    }
  } else {
    // ---- proj + resid (own 1 col-frag, 2 groups) ----
    h4 obf[2][6];
#pragma unroll
    for (int g = 0; g < 2; ++g) {
      const _Float16* orow = obh + (size_t)tok[g] * 96 + lg * 4;
#pragma unroll
      for (int st = 0; st < 6; ++st) obf[g][st] = *(const h4*)(orow + st * 16);
    }
    h4 wf[6];
    const _Float16* wrow = Wp + (size_t)(cfo * 16 + lr) * 96 + lg * 4;
#pragma unroll
    for (int st = 0; st < 6; ++st) wf[st] = *(const h4*)(wrow + st * 16);
    f4 bb = *(const f4*)(bp + cfo * 16 + lg * 4);
#pragma unroll
    for (int g = 0; g < 2; ++g) {
      f4 a = zero4;
#pragma unroll
      for (int st = 0; st < 6; ++st) a = MFMA16(wf[st], obf[g][st], a, 0, 0, 0);
      f4 xr = *(const f4*)(x + (size_t)tok[g] * 96 + cfo * 16 + lg * 4);
#pragma unroll
      for (int j = 0; j < 4; ++j) x1[g][j] = a[j] + bb[j] + xr[j];
    }
    // ---- LN2 partials ----
#pragma unroll
    for (int g = 0; g < 2; ++g) {
      float s = x1[g][0] + x1[g][1] + x1[g][2] + x1[g][3];
      float sq = x1[g][0] * x1[g][0] + x1[g][1] * x1[g][1] +
                 x1[g][2] * x1[g][2] + x1[g][3] * x1[g][3];
      s += __shfl_xor(s, 16); sq += __shfl_xor(sq, 16);
      s += __shfl_xor(s, 32); sq += __shfl_xor(sq, 32);
      if (lane < 16) { LNS(g, wave, lr, 0) = s; LNS(g, wave, lr, 1) = sq; }
    }
    __syncthreads();  // B1
    {
      f4 gg4 = *(const f4*)(ln2g + cfo * 16 + lg * 4);
      f4 b4 = *(const f4*)(ln2b + cfo * 16 + lg * 4);
#pragma unroll
      for (int g = 0; g < 2; ++g) {
        float s = 0.f, sq = 0.f;
#pragma unroll
        for (int w = 0; w < 6; ++w) { s += LNS(g, w, lr, 0); sq += LNS(g, w, lr, 1); }
        float mean = s * (1.f / 96.f);
        float rs = rsqrtf(sq * (1.f / 96.f) - mean * mean + 1e-5f);
        h4 xn;
#pragma unroll
        for (int j = 0; j < 4; ++j)
          xn[j] = (_Float16)((x1[g][j] - mean) * rs * gg4[j] + b4[j]);
        *(h4*)XSH(g, cfo * 16 + lr, lg * 4) = xn;
      }
    }
    __syncthreads();  // B2
    h4 xnf[2][6];
#pragma unroll
    for (int g = 0; g < 2; ++g)
#pragma unroll
      for (int st = 0; st < 6; ++st)
        xnf[g][st] = *(const h4*)XSH(g, st * 16 + lr, lg * 4);
    __syncthreads();  // B2b (xn fully read before HSH overlays it)

    // ---- ff1 + relu -> HSH (own 4 hidden frags) ----
#pragma unroll
    for (int f = 0; f < 4; ++f) {
      int nf = wave * 4 + f;
      h4 w1f[6];
      const _Float16* wr = W1 + (size_t)(nf * 16 + lr) * 96 + lg * 4;
#pragma unroll
      for (int st = 0; st < 6; ++st) w1f[st] = *(const h4*)(wr + st * 16);
      f4 b4 = *(const f4*)(b1 + nf * 16 + lg * 4);
#pragma unroll
      for (int g = 0; g < 2; ++g) {
        f4 h = zero4;
#pragma unroll
        for (int st = 0; st < 6; ++st) h = MFMA16(w1f[st], xnf[g][st], h, 0, 0, 0);
        h4 hv;
#pragma unroll
        for (int j = 0; j < 4; ++j) hv[j] = (_Float16)fmaxf(h[j] + b4[j], 0.f);
        *(h4*)HSH(g, nf, lr, lg * 4) = hv;
      }
    }
    // ---- ff2 (own 1 output frag, full K=384 from HSH) ----
    h4 w2f[24];
    {
      const _Float16* wr = W2 + (size_t)(cfo * 16 + lr) * 384 + lg * 4;
#pragma unroll
      for (int f = 0; f < 24; ++f) w2f[f] = *(const h4*)(wr + f * 16);
    }
    __syncthreads();  // B3 (all hf written)
    {
      f4 b4 = *(const f4*)(b2 + cfo * 16 + lg * 4);
#pragma unroll
      for (int g = 0; g < 2; ++g) {
        f4 y = zero4;
#pragma unroll
        for (int f = 0; f < 24; ++f) {
          h4 hv = *(const h4*)HSH(g, f, lr, lg * 4);
          y = MFMA16(w2f[f], hv, y, 0, 0, 0);
        }
#pragma unroll
        for (int j = 0; j < 4; ++j) xc[g][j] = x1[g][j] + y[j] + b4[j];
        if constexpr (!HEAD)
          *(f4*)(x + (size_t)tok[g] * 96 + cfo * 16 + lg * 4) = xc[g];
      }
    }
  }

  // ---- tail LN on xc ----
#pragma unroll
  for (int g = 0; g < 2; ++g) {
    float s = xc[g][0] + xc[g][1] + xc[g][2] + xc[g][3];
    float sq = xc[g][0] * xc[g][0] + xc[g][1] * xc[g][1] +
               xc[g][2] * xc[g][2] + xc[g][3] * xc[g][3];
    s += __shfl_xor(s, 16); sq += __shfl_xor(sq, 16);
    s += __shfl_xor(s, 32); sq += __shfl_xor(sq, 32);
    if (lane < 16) { LNS(g, wave, lr, 0) = s; LNS(g, wave, lr, 1) = sq; }
  }
  __syncthreads();  // B4 (HSH reads done before XSH overlays)
  {
    f4 gg4 = *(const f4*)(lntg + cfo * 16 + lg * 4);
    f4 b4 = *(const f4*)(lntb + cfo * 16 + lg * 4);
#pragma unroll
    for (int g = 0; g < 2; ++g) {
      float s = 0.f, sq = 0.f;
#pragma unroll
      for (int w = 0; w < 6; ++w) { s += LNS(g, w, lr, 0); sq += LNS(g, w, lr, 1); }
      float mean = s * (1.f / 96.f);
      float rs = rsqrtf(sq * (1.f / 96.f) - mean * mean + 1e-5f);
      h4 xn;
#pragma unroll
      for (int j = 0; j < 4; ++j)
        xn[j] = (_Float16)((xc[g][j] - mean) * rs * gg4[j] + b4[j]);
      *(h4*)XSH(g, cfo * 16 + lr, lg * 4) = xn;
    }
  }
  __syncthreads();  // B5
  if constexpr (HEAD) {
    if (wave == 0) {
      h4 wt[6];
      const _Float16* wr = Wtail + (size_t)lr * 96 + lg * 4;
#pragma unroll
      for (int st = 0; st < 6; ++st) wt[st] = *(const h4*)(wr + st * 16);
      f4 bb = *(const f4*)(btail + lg * 4);
#pragma unroll
      for (int g = 0; g < 2; ++g) {
        f4 a = zero4;
#pragma unroll
        for (int st = 0; st < 6; ++st) {
          h4 xf = *(const h4*)XSH(g, st * 16 + lr, lg * 4);
          a = MFMA16(wt[st], xf, a, 0, 0, 0);
        }
        f4 o;
#pragma unroll
        for (int j = 0; j < 4; ++j) o[j] = a[j] + bb[j];
        *(f4*)(out + (size_t)tok[g] * 16 + lg * 4) = o;
      }
    }
  } else {
    h4 xf[2][6];
#pragma unroll
    for (int g = 0; g < 2; ++g)
#pragma unroll
      for (int st = 0; st < 6; ++st)
        xf[g][st] = *(const h4*)XSH(g, st * 16 + lr, lg * 4);
    // tail frags: nf = wave*3 + f; Q:0-5 K:6-11 V:12-17
#pragma unroll
    for (int f = 0; f < 3; ++f) {
      int nf = wave * 3 + f;
      h4 wt[6];
      const _Float16* wr = Wtail + (size_t)(nf * 16 + lr) * 96 + lg * 4;
#pragma unroll
      for (int st = 0; st < 6; ++st) wt[st] = *(const h4*)(wr + st * 16);
#pragma unroll
      for (int g = 0; g < 2; ++g) {
        f4 a = zero4;
#pragma unroll
        for (int st = 0; st < 6; ++st) a = MFMA16(wt[st], xf[g][st], a, 0, 0, 0);
        if (nf < 12) {  // Q or K: [bh][t][16]
          int h = nf < 6 ? nf : nf - 6;
          _Float16* dst = (nf < 6 ? qh : kh) +
                          (size_t)(bidx * NH_ + h) * 16384 + (size_t)tt[g] * 16 + lg * 4;
          h4 hv = {(_Float16)a[0], (_Float16)a[1], (_Float16)a[2], (_Float16)a[3]};
          *(h4*)dst = hv;
        } else {        // V: [bh][d][1024]
          _Float16* dst = vt + (size_t)(bidx * NH_ + (nf - 12)) * 16384 +
                          (size_t)(lg * 4) * 1024 + tt[g];
#pragma unroll
          for (int r = 0; r < 4; ++r) dst[(size_t)r * 1024] = (_Float16)a[r];
        }
      }
    }
  }
#undef XSH
#undef HSH
#undef LNS
}

// ---------- MFMA f16 flash attention: 32 q-rows/wave, fixed-max softmax ----
// Softmax denominators via ones-MFMA (S += mfma(P, ones)) on the matrix
// pipe: no per-element adds, no cross-lane reduce (S layout == O layout).
__global__ __launch_bounds__(256, 6) void attn_mfma_kernel(
    const _Float16* __restrict__ Qh, const _Float16* __restrict__ Kh,
    const _Float16* __restrict__ Vt, _Float16* __restrict__ obh) {
  int bh = blockIdx.x;
  int wave = threadIdx.x >> 6;
  int lane = threadIdx.x & 63;
  int qb = wave * 8 + blockIdx.y;    // 0..31
  int q0 = qb * 32;
  int lr = lane & 15;
  int lg = lane >> 4;

  const _Float16* qp = Qh + (size_t)bh * 16384;
  const _Float16* kb = Kh + (size_t)bh * 16384;
  const _Float16* vb = Vt + (size_t)bh * 16384;

  h4 qf0 = *(const h4*)(qp + (size_t)(q0 + lr) * 16 + lg * 4);
  h4 qf1 = *(const h4*)(qp + (size_t)(q0 + 16 + lr) * 16 + lg * 4);
  f4 O0 = {0.f, 0.f, 0.f, 0.f}, O1 = {0.f, 0.f, 0.f, 0.f};
  f4 S0 = {0.f, 0.f, 0.f, 0.f}, S1 = {0.f, 0.f, 0.f, 0.f};
  const f4 zero4 = {0.f, 0.f, 0.f, 0.f};
  const h4 ones = {(_Float16)1.f, (_Float16)1.f, (_Float16)1.f, (_Float16)1.f};

  h4 kc0, kc1, vc0, vc1, kn0, kn1, vn0, vn1;
  kc0 = *(const h4*)(kb + (size_t)lr * 16 + lg * 4);
  kc1 = *(const h4*)(kb + (size_t)(16 + lr) * 16 + lg * 4);
  vc0 = *(const h4*)(vb + (size_t)lr * 1024 + lg * 4);
  vc1 = *(const h4*)(vb + (size_t)lr * 1024 + 16 + lg * 4);

  for (int tt = 0; tt < qb; ++tt) {
    int s1 = tt * 32 + 32;
    kn0 = *(const h4*)(kb + (size_t)(s1 + lr) * 16 + lg * 4);
    kn1 = *(const h4*)(kb + (size_t)(s1 + 16 + lr) * 16 + lg * 4);
    vn0 = *(const h4*)(vb + (size_t)lr * 1024 + s1 + lg * 4);
    vn1 = *(const h4*)(vb + (size_t)lr * 1024 + s1 + 16 + lg * 4);

    f4 sa0 = MFMA16(kc0, qf0, zero4, 0, 0, 0);
    f4 sa1 = MFMA16(kc1, qf0, zero4, 0, 0, 0);
    f4 sb0 = MFMA16(kc0, qf1, zero4, 0, 0, 0);
    f4 sb1 = MFMA16(kc1, qf1, zero4, 0, 0, 0);
    float pa0[4], pa1[4], pb0[4], pb1[4];
#pragma unroll
    for (int r = 0; r < 4; ++r) {
      pa0[r] = __builtin_amdgcn_exp2f(sa0[r]);
      pa1[r] = __builtin_amdgcn_exp2f(sa1[r]);
      pb0[r] = __builtin_amdgcn_exp2f(sb0[r]);
      pb1[r] = __builtin_amdgcn_exp2f(sb1[r]);
    }
    h4 fa0 = pk4(pa0), fa1 = pk4(pa1), fb0 = pk4(pb0), fb1 = pk4(pb1);
    O0 = MFMA16(fa0, vc0, O0, 0, 0, 0);
    O0 = MFMA16(fa1, vc1, O0, 0, 0, 0);
    S0 = MFMA16(fa0, ones, S0, 0, 0, 0);
    S0 = MFMA16(fa1, ones, S0, 0, 0, 0);
    O1 = MFMA16(fb0, vc0, O1, 0, 0, 0);
    O1 = MFMA16(fb1, vc1, O1, 0, 0, 0);
    S1 = MFMA16(fb0, ones, S1, 0, 0, 0);
    S1 = MFMA16(fb1, ones, S1, 0, 0, 0);
    kc0 = kn0; kc1 = kn1; vc0 = vn0; vc1 = vn1;
  }

  {
    f4 sa0 = MFMA16(kc0, qf0, zero4, 0, 0, 0);
    float pa0[4];
#pragma unroll
    for (int r = 0; r < 4; ++r)
      pa0[r] = (lg * 4 + r <= lr) ? __builtin_amdgcn_exp2f(sa0[r]) : 0.f;
    h4 fa0 = pk4(pa0);
    O0 = MFMA16(fa0, vc0, O0, 0, 0, 0);
    S0 = MFMA16(fa0, ones, S0, 0, 0, 0);

    f4 sb0 = MFMA16(kc0, qf1, zero4, 0, 0, 0);
    f4 sb1 = MFMA16(kc1, qf1, zero4, 0, 0, 0);
    float pb0[4], pb1[4];
#pragma unroll
    for (int r = 0; r < 4; ++r) {
      pb0[r] = __builtin_amdgcn_exp2f(sb0[r]);
      pb1[r] = (lg * 4 + r <= lr) ? __builtin_amdgcn_exp2f(sb1[r]) : 0.f;
    }
    h4 fb0 = pk4(pb0), fb1 = pk4(pb1);
    O1 = MFMA16(fb0, vc0, O1, 0, 0, 0);
    O1 = MFMA16(fb1, vc1, O1, 0, 0, 0);
    S1 = MFMA16(fb0, ones, S1, 0, 0, 0);
    S1 = MFMA16(fb1, ones, S1, 0, 0, 0);
  }

  int b = bh / NH_, h = bh % NH_;
#pragma unroll
  for (int r = 0; r < 4; ++r) {
    int qa = q0 + lg * 4 + r;
    float li0 = __builtin_amdgcn_rcpf(S0[r]);
    float li1 = __builtin_amdgcn_rcpf(S1[r]);
    obh[(size_t)(b * 1024 + qa) * 96 + h * 16 + lr] = (_Float16)(O0[r] * li0);
    obh[(size_t)(b * 1024 + qa + 16) * 96 + h * 16 + lr] = (_Float16)(O1[r] * li1);
  }
}

extern "C" void kernel_launch(void* const* d_in, const int* in_sizes, int n_in,
                              void* d_out, int out_size, void* d_ws, size_t ws_size,
                              hipStream_t stream) {
  const float* goals   = (const float*)d_in[0];
  const float* obss    = (const float*)d_in[1];
  const float* w_go    = (const float*)d_in[2];
  const float* b_go    = (const float*)d_in[3];
  const float* pos_emb = (const float*)d_in[4];
  const float* wq      = (const float*)d_in[5];
  const float* wk      = (const float*)d_in[6];
  const float* wv      = (const float*)d_in[7];
  const float* w_proj  = (const float*)d_in[8];
  const float* b_proj  = (const float*)d_in[9];
  const float* ln1_g   = (const float*)d_in[10];
  const float* ln1_b   = (const float*)d_in[11];
  const float* ln2_g   = (const float*)d_in[12];
  const float* ln2_b   = (const float*)d_in[13];
  const float* w_ff1   = (const float*)d_in[14];
  const float* b_ff1   = (const float*)d_in[15];
  const float* w_ff2   = (const float*)d_in[16];
  const float* b_ff2   = (const float*)d_in[17];
  const float* lnf_g   = (const float*)d_in[18];
  const float* lnf_b   = (const float*)d_in[19];
  const float* w_act   = (const float*)d_in[20];
  const float* b_act   = (const float*)d_in[21];
  float* out = (float*)d_out;

  const int M = B_ * T_;  // 16384
  float* ws = (float*)d_ws;
  size_t off = 0;
  _Float16* P = (_Float16*)(ws + off); off += PACK_TOTAL / 2 + 64;
  float* x = ws + off; off += (size_t)M * 96;
  _Float16* obh = (_Float16*)(ws + off); off += (size_t)M * 48;
  _Float16* Qh = (_Float16*)(ws + off); off += (size_t)M * 48;
  _Float16* Kh = (_Float16*)(ws + off); off += (size_t)M * 48;
  _Float16* Vt = (_Float16*)(ws + off); off += (size_t)M * 48;

  pack_all_kernel<<<(PACK_TOTAL + 255) / 256, 256, 0, stream>>>(
      w_go, wq, wk, wv, w_proj, w_ff1, w_ff2, w_act, P);

  // embed + qkv(layer 0)
  stage_kernel<true, false><<<M / 32, 384, 0, stream>>>(
      goals, obss, pos_emb, b_go, nullptr, P + OFF_GO, nullptr, x,
      nullptr, nullptr, nullptr, nullptr, nullptr, nullptr,
      ln1_g, ln1_b, P + OFF_QKV, nullptr, Qh, Kh, Vt, nullptr);

  for (int l = 0; l < L_; ++l) {
    attn_mfma_kernel<<<dim3(B_ * NH_, 8), 256, 0, stream>>>(Qh, Kh, Vt, obh);
    if (l < L_ - 1) {
      stage_kernel<false, false><<<M / 32, 384, 0, stream>>>(
          nullptr, nullptr, nullptr, nullptr, obh,
          P + OFF_PROJ + (size_t)l * 9216, b_proj + l * 96, x,
          P + OFF_FF1 + (size_t)l * 36864, b_ff1 + l * 384,
          P + OFF_FF2 + (size_t)l * 36864, b_ff2 + l * 96,
          ln2_g + l * 96, ln2_b + l * 96,
          ln1_g + (l + 1) * 96, ln1_b + (l + 1) * 96,
          P + OFF_QKV + (size_t)(l + 1) * 27648, nullptr, Qh, Kh, Vt, nullptr);
    } else {
      stage_kernel<false, true><<<M / 32, 384, 0, stream>>>(
          nullptr, nullptr, nullptr, nullptr, obh,
          P + OFF_PROJ + (size_t)l * 9216, b_proj + l * 96, x,
          P + OFF_FF1 + (size_t)l * 36864, b_ff1 + l * 384,
          P + OFF_FF2 + (size_t)l * 36864, b_ff2 + l * 96,
          ln2_g + l * 96, ln2_b + l * 96,
          lnf_g, lnf_b, P + OFF_ACT, b_act, nullptr, nullptr, nullptr, out);
    }
  }
}

// Round 17
// 242.459 us; speedup vs baseline: 1.2605x; 1.2605x over previous
//
#include <hip/hip_runtime.h>
#include <math.h>

#define B_ 16
#define T_ 1024
#define D_ 96
#define L_ 6
#define NH_ 6
#define HS_ 16
#define FF_ 384

typedef _Float16 h4 __attribute__((ext_vector_type(4)));
typedef _Float16 h8 __attribute__((ext_vector_type(8)));
typedef __fp16 g2 __attribute__((ext_vector_type(2)));
typedef __fp16 g4 __attribute__((ext_vector_type(4)));
typedef float f4 __attribute__((ext_vector_type(4)));

#define MFMA16 __builtin_amdgcn_mfma_f32_16x16x16f16

// packed f16 weights, layout [frag][stp][lane 0..63][8 halves]:
// halves 0..3 = k-slice 2*stp, 4..7 = k-slice 2*stp+1, for row frag*16+(lane&15),
// cols st*16+(lane>>4)*4 .. +4. One 16-B lane load = 2 MFMA B-fragments,
// wave load = contiguous 1 KB.
#define OFF_GO   0
#define OFF_QKV  9216
#define OFF_PROJ 175104
#define OFF_FF1  230400
#define OFF_FF2  451584
#define OFF_ACT  672768
#define PACK_TOTAL 674304

// Q weights pre-scaled by 1/sqrt(16) * log2(e) so attn uses exp2 directly.
#define QSCALE 0.3606737602222409f

static __device__ __forceinline__ h4 pk4(const float* p) {
  g2 lo = __builtin_amdgcn_cvt_pkrtz(p[0], p[1]);
  g2 hi = __builtin_amdgcn_cvt_pkrtz(p[2], p[3]);
  g4 r4 = __builtin_shufflevector(lo, hi, 0, 1, 2, 3);
  return __builtin_bit_cast(h4, r4);
}

static __device__ __forceinline__ void ldpair(const _Float16* base, int blk,
                                              int lane, h4& a, h4& b) {
  h8 t = *(const h8*)(base + (size_t)blk * 512 + lane * 8);
  a = __builtin_shufflevector(t, t, 0, 1, 2, 3);
  b = __builtin_shufflevector(t, t, 4, 5, 6, 7);
}

// ---------- pack all weights into paired-fragment layout ----------
__global__ __launch_bounds__(256) void pack_all_kernel(
    const float* __restrict__ w_go, const float* __restrict__ wq,
    const float* __restrict__ wk, const float* __restrict__ wv,
    const float* __restrict__ w_proj, const float* __restrict__ w_ff1,
    const float* __restrict__ w_ff2, const float* __restrict__ w_act,
    _Float16* __restrict__ P) {
  int i = blockIdx.x * 256 + threadIdx.x;
  if (i >= PACK_TOTAL) return;
  float v;
  if (i < OFF_QKV) {                       // GO: 6 frags, 3 stp
    int o = i, nf = o / 1536, r = o % 1536, stp = r / 512, q = r & 511;
    int lane = q >> 3, h8i = q & 7, lr = lane & 15, lg = lane >> 4;
    int st = stp * 2 + (h8i >> 2), j = h8i & 3;
    int n = nf * 16 + lr, k = st * 16 + lg * 4 + j;
    v = w_go[k * 96 + n];
  } else if (i < OFF_PROJ) {               // QKV: per layer 18 frags, 3 stp
    int o = i - OFF_QKV, l = o / 27648, r0 = o % 27648;
    int nf = r0 / 1536, r = r0 % 1536, stp = r / 512, q = r & 511;
    int lane = q >> 3, h8i = q & 7, lr = lane & 15, lg = lane >> 4;
    int st = stp * 2 + (h8i >> 2), j = h8i & 3;
    int c = nf * 16 + lr, k = st * 16 + lg * 4 + j;
    int which = c / 96, hc = c % 96, h = hc >> 4, jx = hc & 15;
    const float* s = (which == 0) ? wq : (which == 1 ? wk : wv);
    v = s[((l * NH_ + h) * 96 + k) * 16 + jx];
    if (which == 0) v *= QSCALE;
  } else if (i < OFF_FF1) {                // PROJ: per layer 6 frags, 3 stp
    int o = i - OFF_PROJ, l = o / 9216, r0 = o % 9216;
    int nf = r0 / 1536, r = r0 % 1536, stp = r / 512, q = r & 511;
    int lane = q >> 3, h8i = q & 7, lr = lane & 15, lg = lane >> 4;
    int st = stp * 2 + (h8i >> 2), j = h8i & 3;
    int n = nf * 16 + lr, k = st * 16 + lg * 4 + j;
    v = w_proj[l * 9216 + k * 96 + n];
  } else if (i < OFF_FF2) {                // FF1: per layer 24 frags, 3 stp
    int o = i - OFF_FF1, l = o / 36864, r0 = o % 36864;
    int nf = r0 / 1536, r = r0 % 1536, stp = r / 512, q = r & 511;
    int lane = q >> 3, h8i = q & 7, lr = lane & 15, lg = lane >> 4;
    int st = stp * 2 + (h8i >> 2), j = h8i & 3;
    int n = nf * 16 + lr, k = st * 16 + lg * 4 + j;
    v = w_ff1[l * 36864 + k * 384 + n];
  } else if (i < OFF_ACT) {                // FF2: per layer 6 frags, 12 stp
    int o = i - OFF_FF2, l = o / 36864, r0 = o % 36864;
    int nf = r0 / 6144, r = r0 % 6144, stp = r / 512, q = r & 511;
    int lane = q >> 3, h8i = q & 7, lr = lane & 15, lg = lane >> 4;
    int st = stp * 2 + (h8i >> 2), j = h8i & 3;
    int n = nf * 16 + lr, k = st * 16 + lg * 4 + j;
    v = w_ff2[l * 36864 + k * 96 + n];
  } else {                                 // ACT: 1 frag, 3 stp
    int o = i - OFF_ACT, stp = o / 512, q = o & 511;
    int lane = q >> 3, h8i = q & 7, lr = lane & 15, lg = lane >> 4;
    int st = stp * 2 + (h8i >> 2), j = h8i & 3;
    int k = st * 16 + lg * 4 + j;
    v = w_act[k * 16 + lr];
  }
  P[i] = (_Float16)v;
}

// ---------- fused stage kernel: 6 waves x 4 token-groups (64 tokens) ------
template <bool EMBED, bool HEAD>
__global__ __launch_bounds__(384, 1) void stage_kernel(
    const float* __restrict__ goals, const float* __restrict__ obss,
    const float* __restrict__ pos, const float* __restrict__ b_go,
    const _Float16* __restrict__ obh, const _Float16* __restrict__ Wp,
    const float* __restrict__ bp, float* __restrict__ x,
    const _Float16* __restrict__ W1, const float* __restrict__ b1,
    const _Float16* __restrict__ W2, const float* __restrict__ b2,
    const float* __restrict__ ln2g, const float* __restrict__ ln2b,
    const float* __restrict__ lntg, const float* __restrict__ lntb,
    const _Float16* __restrict__ Wtail, const float* __restrict__ btail,
    _Float16* __restrict__ qh, _Float16* __restrict__ kh,
    _Float16* __restrict__ vt, float* __restrict__ out) {
  __shared__ float smemf[16128];  // 64512 B
#define XSH(g, row, c) ((_Float16*)smemf + (size_t)(g) * 1920 + (row) * 20 + (c))
#define HSH(g, f, r, c) ((_Float16*)smemf + (size_t)(g) * 7680 + ((f) * 16 + (r)) * 20 + (c))
#define LNS(g, w, r, i) smemf[15360 + (((g) * 6 + (w)) * 16 + (r)) * 2 + (i)]
  const int tid = threadIdx.x;
  const int wave = tid >> 6, lane = tid & 63;
  const int lr = lane & 15, lg = lane >> 4;
  const int row0 = blockIdx.x * 64;
  const int bidx = row0 >> 10;
  const int cfo = wave;  // owned col-frag 0..5
  const f4 zero4 = {0.f, 0.f, 0.f, 0.f};
  int tok[4], tt[4];
#pragma unroll
  for (int g = 0; g < 4; ++g) { tok[g] = row0 + g * 16 + lr; tt[g] = tok[g] & 1023; }

  f4 xc[4], x1[4];

  if constexpr (EMBED) {
    h4 ef[4][6];
#pragma unroll
    for (int st = 0; st < 2; ++st) {
      f4 s4 = *(const f4*)(goals + bidx * 32 + st * 16 + lg * 4);
      h4 e = (h4){(_Float16)s4[0], (_Float16)s4[1], (_Float16)s4[2], (_Float16)s4[3]};
#pragma unroll
      for (int g = 0; g < 4; ++g) ef[g][st] = e;
    }
#pragma unroll
    for (int g = 0; g < 4; ++g)
#pragma unroll
      for (int st = 2; st < 6; ++st) {
        f4 s4 = *(const f4*)(obss + (size_t)(bidx * 1024 + tt[g]) * 64 +
                             (st - 2) * 16 + lg * 4);
        ef[g][st] = (h4){(_Float16)s4[0], (_Float16)s4[1], (_Float16)s4[2], (_Float16)s4[3]};
      }
    h4 wf[6];
#pragma unroll
    for (int stp = 0; stp < 3; ++stp)
      ldpair(Wp, cfo * 3 + stp, lane, wf[2 * stp], wf[2 * stp + 1]);
    f4 bb = *(const f4*)(b_go + cfo * 16 + lg * 4);
#pragma unroll
    for (int g = 0; g < 4; ++g) {
      f4 a = zero4;
#pragma unroll
      for (int st = 0; st < 6; ++st) a = MFMA16(wf[st], ef[g][st], a, 0, 0, 0);
      f4 pp = *(const f4*)(pos + (size_t)tt[g] * 96 + cfo * 16 + lg * 4);
#pragma unroll
      for (int j = 0; j < 4; ++j) xc[g][j] = a[j] + bb[j] + pp[j];
      *(f4*)(x + (size_t)tok[g] * 96 + cfo * 16 + lg * 4) = xc[g];
    }
  } else {
    // ---- proj + resid (own 1 col-frag, 4 groups) ----
    h4 obf[4][6];
#pragma unroll
    for (int g = 0; g < 4; ++g) {
      const _Float16* orow = obh + (size_t)tok[g] * 96 + lg * 4;
#pragma unroll
      for (int st = 0; st < 6; ++st) obf[g][st] = *(const h4*)(orow + st * 16);
    }
    h4 wf[6];
#pragma unroll
    for (int stp = 0; stp < 3; ++stp)
      ldpair(Wp, cfo * 3 + stp, lane, wf[2 * stp], wf[2 * stp + 1]);
    f4 bb = *(const f4*)(bp + cfo * 16 + lg * 4);
#pragma unroll
    for (int g = 0; g < 4; ++g) {
      f4 a = zero4;
#pragma unroll
      for (int st = 0; st < 6; ++st) a = MFMA16(wf[st], obf[g][st], a, 0, 0, 0);
      f4 xr = *(const f4*)(x + (size_t)tok[g] * 96 + cfo * 16 + lg * 4);
#pragma unroll
      for (int j = 0; j < 4; ++j) x1[g][j] = a[j] + bb[j] + xr[j];
    }
    // ---- LN2 partials ----
#pragma unroll
    for (int g = 0; g < 4; ++g) {
      float s = x1[g][0] + x1[g][1] + x1[g][2] + x1[g][3];
      float sq = x1[g][0] * x1[g][0] + x1[g][1] * x1[g][1] +
                 x1[g][2] * x1[g][2] + x1[g][3] * x1[g][3];
      s += __shfl_xor(s, 16); sq += __shfl_xor(sq, 16);
      s += __shfl_xor(s, 32); sq += __shfl_xor(sq, 32);
      if (lane < 16) { LNS(g, wave, lr, 0) = s; LNS(g, wave, lr, 1) = sq; }
    }
    __syncthreads();  // B1
    {
      f4 gg4 = *(const f4*)(ln2g + cfo * 16 + lg * 4);
      f4 b4 = *(const f4*)(ln2b + cfo * 16 + lg * 4);
#pragma unroll
      for (int g = 0; g < 4; ++g) {
        float s = 0.f, sq = 0.f;
#pragma unroll
        for (int w = 0; w < 6; ++w) { s += LNS(g, w, lr, 0); sq += LNS(g, w, lr, 1); }
        float mean = s * (1.f / 96.f);
        float rs = rsqrtf(sq * (1.f / 96.f) - mean * mean + 1e-5f);
        h4 xn;
#pragma unroll
        for (int j = 0; j < 4; ++j)
          xn[j] = (_Float16)((x1[g][j] - mean) * rs * gg4[j] + b4[j]);
        *(h4*)XSH(g, cfo * 16 + lr, lg * 4) = xn;
      }
    }
    __syncthreads();  // B2
    h4 xnf[4][6];
#pragma unroll
    for (int g = 0; g < 4; ++g)
#pragma unroll
      for (int st = 0; st < 6; ++st)
        xnf[g][st] = *(const h4*)XSH(g, st * 16 + lr, lg * 4);
    __syncthreads();  // B2b (xn fully read before HSH overlays it)

    // ---- ff1 + relu -> HSH (own 4 hidden frags) ----
#pragma unroll
    for (int f = 0; f < 4; ++f) {
      int nf = wave * 4 + f;
      h4 w1f[6];
#pragma unroll
      for (int stp = 0; stp < 3; ++stp)
        ldpair(W1, nf * 3 + stp, lane, w1f[2 * stp], w1f[2 * stp + 1]);
      f4 b4 = *(const f4*)(b1 + nf * 16 + lg * 4);
#pragma unroll
      for (int g = 0; g < 4; ++g) {
        f4 h = zero4;
#pragma unroll
        for (int st = 0; st < 6; ++st) h = MFMA16(w1f[st], xnf[g][st], h, 0, 0, 0);
        h4 hv;
#pragma unroll
        for (int j = 0; j < 4; ++j) hv[j] = (_Float16)fmaxf(h[j] + b4[j], 0.f);
        *(h4*)HSH(g, nf, lr, lg * 4) = hv;
      }
    }
    // ---- ff2 (own 1 output frag, full K=384 from HSH) ----
    h4 w2f[24];
#pragma unroll
    for (int stp = 0; stp < 12; ++stp)
      ldpair(W2, cfo * 12 + stp, lane, w2f[2 * stp], w2f[2 * stp + 1]);
    __syncthreads();  // B3 (all hf written)
    {
      f4 b4 = *(const f4*)(b2 + cfo * 16 + lg * 4);
#pragma unroll
      for (int g = 0; g < 4; ++g) {
        f4 y = zero4;
#pragma unroll
        for (int f = 0; f < 24; ++f) {
          h4 hv = *(const h4*)HSH(g, f, lr, lg * 4);
          y = MFMA16(w2f[f], hv, y, 0, 0, 0);
        }
#pragma unroll
        for (int j = 0; j < 4; ++j) xc[g][j] = x1[g][j] + y[j] + b4[j];
        if constexpr (!HEAD)
          *(f4*)(x + (size_t)tok[g] * 96 + cfo * 16 + lg * 4) = xc[g];
      }
    }
  }

  // ---- tail LN on xc ----
#pragma unroll
  for (int g = 0; g < 4; ++g) {
    float s = xc[g][0] + xc[g][1] + xc[g][2] + xc[g][3];
    float sq = xc[g][0] * xc[g][0] + xc[g][1] * xc[g][1] +
               xc[g][2] * xc[g][2] + xc[g][3] * xc[g][3];
    s += __shfl_xor(s, 16); sq += __shfl_xor(sq, 16);
    s += __shfl_xor(s, 32); sq += __shfl_xor(sq, 32);
    if (lane < 16) { LNS(g, wave, lr, 0) = s; LNS(g, wave, lr, 1) = sq; }
  }
  __syncthreads();  // B4 (all HSH reads done before XSH overlays)
  {
    f4 gg4 = *(const f4*)(lntg + cfo * 16 + lg * 4);
    f4 b4 = *(const f4*)(lntb + cfo * 16 + lg * 4);
#pragma unroll
    for (int g = 0; g < 4; ++g) {
      float s = 0.f, sq = 0.f;
#pragma unroll
      for (int w = 0; w < 6; ++w) { s += LNS(g, w, lr, 0); sq += LNS(g, w, lr, 1); }
      float mean = s * (1.f / 96.f);
      float rs = rsqrtf(sq * (1.f / 96.f) - mean * mean + 1e-5f);
      h4 xn;
#pragma unroll
      for (int j = 0; j < 4; ++j)
        xn[j] = (_Float16)((xc[g][j] - mean) * rs * gg4[j] + b4[j]);
      *(h4*)XSH(g, cfo * 16 + lr, lg * 4) = xn;
    }
  }
  __syncthreads();  // B5
  if constexpr (HEAD) {
    if (wave == 0) {
      h4 wt[6];
#pragma unroll
      for (int stp = 0; stp < 3; ++stp)
        ldpair(Wtail, stp, lane, wt[2 * stp], wt[2 * stp + 1]);
      f4 bb = *(const f4*)(btail + lg * 4);
#pragma unroll
      for (int g = 0; g < 4; ++g) {
        f4 a = zero4;
#pragma unroll
        for (int st = 0; st < 6; ++st) {
          h4 xf = *(const h4*)XSH(g, st * 16 + lr, lg * 4);
          a = MFMA16(wt[st], xf, a, 0, 0, 0);
        }
        f4 o;
#pragma unroll
        for (int j = 0; j < 4; ++j) o[j] = a[j] + bb[j];
        *(f4*)(out + (size_t)tok[g] * 16 + lg * 4) = o;
      }
    }
  } else {
    h4 xf[4][6];
#pragma unroll
    for (int g = 0; g < 4; ++g)
#pragma unroll
      for (int st = 0; st < 6; ++st)
        xf[g][st] = *(const h4*)XSH(g, st * 16 + lr, lg * 4);
    // tail frags: nf = wave*3 + f; Q:0-5 K:6-11 V:12-17
#pragma unroll
    for (int f = 0; f < 3; ++f) {
      int nf = wave * 3 + f;
      h4 wt[6];
#pragma unroll
      for (int stp = 0; stp < 3; ++stp)
        ldpair(Wtail, nf * 3 + stp, lane, wt[2 * stp], wt[2 * stp + 1]);
#pragma unroll
      for (int g = 0; g < 4; ++g) {
        f4 a = zero4;
#pragma unroll
        for (int st = 0; st < 6; ++st) a = MFMA16(wt[st], xf[g][st], a, 0, 0, 0);
        if (nf < 12) {  // Q or K: [bh][t][16]
          int h = nf < 6 ? nf : nf - 6;
          _Float16* dst = (nf < 6 ? qh : kh) +
                          (size_t)(bidx * NH_ + h) * 16384 + (size_t)tt[g] * 16 + lg * 4;
          h4 hv = {(_Float16)a[0], (_Float16)a[1], (_Float16)a[2], (_Float16)a[3]};
          *(h4*)dst = hv;
        } else {        // V: [bh][d][1024]
          _Float16* dst = vt + (size_t)(bidx * NH_ + (nf - 12)) * 16384 +
                          (size_t)(lg * 4) * 1024 + tt[g];
#pragma unroll
          for (int r = 0; r < 4; ++r) dst[(size_t)r * 1024] = (_Float16)a[r];
        }
      }
    }
  }
#undef XSH
#undef HSH
#undef LNS
}

// ---------- MFMA f16 flash attention: 32 q-rows/wave, fixed-max softmax ----
// Softmax denominators via ones-MFMA (S += mfma(P, ones)) on the matrix
// pipe: no per-element adds, no cross-lane reduce (S layout == O layout).
__global__ __launch_bounds__(256, 6) void attn_mfma_kernel(
    const _Float16* __restrict__ Qh, const _Float16* __restrict__ Kh,
    const _Float16* __restrict__ Vt, _Float16* __restrict__ obh) {
  int bh = blockIdx.x;
  int wave = threadIdx.x >> 6;
  int lane = threadIdx.x & 63;
  int qb = wave * 8 + blockIdx.y;    // 0..31
  int q0 = qb * 32;
  int lr = lane & 15;
  int lg = lane >> 4;

  const _Float16* qp = Qh + (size_t)bh * 16384;
  const _Float16* kb = Kh + (size_t)bh * 16384;
  const _Float16* vb = Vt + (size_t)bh * 16384;

  h4 qf0 = *(const h4*)(qp + (size_t)(q0 + lr) * 16 + lg * 4);
  h4 qf1 = *(const h4*)(qp + (size_t)(q0 + 16 + lr) * 16 + lg * 4);
  f4 O0 = {0.f, 0.f, 0.f, 0.f}, O1 = {0.f, 0.f, 0.f, 0.f};
  f4 S0 = {0.f, 0.f, 0.f, 0.f}, S1 = {0.f, 0.f, 0.f, 0.f};
  const f4 zero4 = {0.f, 0.f, 0.f, 0.f};
  const h4 ones = {(_Float16)1.f, (_Float16)1.f, (_Float16)1.f, (_Float16)1.f};

  h4 kc0, kc1, vc0, vc1, kn0, kn1, vn0, vn1;
  kc0 = *(const h4*)(kb + (size_t)lr * 16 + lg * 4);
  kc1 = *(const h4*)(kb + (size_t)(16 + lr) * 16 + lg * 4);
  vc0 = *(const h4*)(vb + (size_t)lr * 1024 + lg * 4);
  vc1 = *(const h4*)(vb + (size_t)lr * 1024 + 16 + lg * 4);

  for (int tt = 0; tt < qb; ++tt) {
    int s1 = tt * 32 + 32;
    kn0 = *(const h4*)(kb + (size_t)(s1 + lr) * 16 + lg * 4);
    kn1 = *(const h4*)(kb + (size_t)(s1 + 16 + lr) * 16 + lg * 4);
    vn0 = *(const h4*)(vb + (size_t)lr * 1024 + s1 + lg * 4);
    vn1 = *(const h4*)(vb + (size_t)lr * 1024 + s1 + 16 + lg * 4);

    f4 sa0 = MFMA16(kc0, qf0, zero4, 0, 0, 0);
    f4 sa1 = MFMA16(kc1, qf0, zero4, 0, 0, 0);
    f4 sb0 = MFMA16(kc0, qf1, zero4, 0, 0, 0);
    f4 sb1 = MFMA16(kc1, qf1, zero4, 0, 0, 0);
    float pa0[4], pa1[4], pb0[4], pb1[4];
#pragma unroll
    for (int r = 0; r < 4; ++r) {
      pa0[r] = __builtin_amdgcn_exp2f(sa0[r]);
      pa1[r] = __builtin_amdgcn_exp2f(sa1[r]);
      pb0[r] = __builtin_amdgcn_exp2f(sb0[r]);
      pb1[r] = __builtin_amdgcn_exp2f(sb1[r]);
    }
    h4 fa0 = pk4(pa0), fa1 = pk4(pa1), fb0 = pk4(pb0), fb1 = pk4(pb1);
    O0 = MFMA16(fa0, vc0, O0, 0, 0, 0);
    O0 = MFMA16(fa1, vc1, O0, 0, 0, 0);
    S0 = MFMA16(fa0, ones, S0, 0, 0, 0);
    S0 = MFMA16(fa1, ones, S0, 0, 0, 0);
    O1 = MFMA16(fb0, vc0, O1, 0, 0, 0);
    O1 = MFMA16(fb1, vc1, O1, 0, 0, 0);
    S1 = MFMA16(fb0, ones, S1, 0, 0, 0);
    S1 = MFMA16(fb1, ones, S1, 0, 0, 0);
    kc0 = kn0; kc1 = kn1; vc0 = vn0; vc1 = vn1;
  }

  {
    f4 sa0 = MFMA16(kc0, qf0, zero4, 0, 0, 0);
    float pa0[4];
#pragma unroll
    for (int r = 0; r < 4; ++r)
      pa0[r] = (lg * 4 + r <= lr) ? __builtin_amdgcn_exp2f(sa0[r]) : 0.f;
    h4 fa0 = pk4(pa0);
    O0 = MFMA16(fa0, vc0, O0, 0, 0, 0);
    S0 = MFMA16(fa0, ones, S0, 0, 0, 0);

    f4 sb0 = MFMA16(kc0, qf1, zero4, 0, 0, 0);
    f4 sb1 = MFMA16(kc1, qf1, zero4, 0, 0, 0);
    float pb0[4], pb1[4];
#pragma unroll
    for (int r = 0; r < 4; ++r) {
      pb0[r] = __builtin_amdgcn_exp2f(sb0[r]);
      pb1[r] = (lg * 4 + r <= lr) ? __builtin_amdgcn_exp2f(sb1[r]) : 0.f;
    }
    h4 fb0 = pk4(pb0), fb1 = pk4(pb1);
    O1 = MFMA16(fb0, vc0, O1, 0, 0, 0);
    O1 = MFMA16(fb1, vc1, O1, 0, 0, 0);
    S1 = MFMA16(fb0, ones, S1, 0, 0, 0);
    S1 = MFMA16(fb1, ones, S1, 0, 0, 0);
  }

  int b = bh / NH_, h = bh % NH_;
#pragma unroll
  for (int r = 0; r < 4; ++r) {
    int qa = q0 + lg * 4 + r;
    float li0 = __builtin_amdgcn_rcpf(S0[r]);
    float li1 = __builtin_amdgcn_rcpf(S1[r]);
    obh[(size_t)(b * 1024 + qa) * 96 + h * 16 + lr] = (_Float16)(O0[r] * li0);
    obh[(size_t)(b * 1024 + qa + 16) * 96 + h * 16 + lr] = (_Float16)(O1[r] * li1);
  }
}

extern "C" void kernel_launch(void* const* d_in, const int* in_sizes, int n_in,
                              void* d_out, int out_size, void* d_ws, size_t ws_size,
                              hipStream_t stream) {
  const float* goals   = (const float*)d_in[0];
  const float* obss    = (const float*)d_in[1];
  const float* w_go    = (const float*)d_in[2];
  const float* b_go    = (const float*)d_in[3];
  const float* pos_emb = (const float*)d_in[4];
  const float* wq      = (const float*)d_in[5];
  const float* wk      = (const float*)d_in[6];
  const float* wv      = (const float*)d_in[7];
  const float* w_proj  = (const float*)d_in[8];
  const float* b_proj  = (const float*)d_in[9];
  const float* ln1_g   = (const float*)d_in[10];
  const float* ln1_b   = (const float*)d_in[11];
  const float* ln2_g   = (const float*)d_in[12];
  const float* ln2_b   = (const float*)d_in[13];
  const float* w_ff1   = (const float*)d_in[14];
  const float* b_ff1   = (const float*)d_in[15];
  const float* w_ff2   = (const float*)d_in[16];
  const float* b_ff2   = (const float*)d_in[17];
  const float* lnf_g   = (const float*)d_in[18];
  const float* lnf_b   = (const float*)d_in[19];
  const float* w_act   = (const float*)d_in[20];
  const float* b_act   = (const float*)d_in[21];
  float* out = (float*)d_out;

  const int M = B_ * T_;  // 16384
  float* ws = (float*)d_ws;
  size_t off = 0;
  _Float16* P = (_Float16*)(ws + off); off += PACK_TOTAL / 2 + 64;
  float* x = ws + off; off += (size_t)M * 96;
  _Float16* obh = (_Float16*)(ws + off); off += (size_t)M * 48;
  _Float16* Qh = (_Float16*)(ws + off); off += (size_t)M * 48;
  _Float16* Kh = (_Float16*)(ws + off); off += (size_t)M * 48;
  _Float16* Vt = (_Float16*)(ws + off); off += (size_t)M * 48;

  pack_all_kernel<<<(PACK_TOTAL + 255) / 256, 256, 0, stream>>>(
      w_go, wq, wk, wv, w_proj, w_ff1, w_ff2, w_act, P);

  // embed + qkv(layer 0)
  stage_kernel<true, false><<<M / 64, 384, 0, stream>>>(
      goals, obss, pos_emb, b_go, nullptr, P + OFF_GO, nullptr, x,
      nullptr, nullptr, nullptr, nullptr, nullptr, nullptr,
      ln1_g, ln1_b, P + OFF_QKV, nullptr, Qh, Kh, Vt, nullptr);

  for (int l = 0; l < L_; ++l) {
    attn_mfma_kernel<<<dim3(B_ * NH_, 8), 256, 0, stream>>>(Qh, Kh, Vt, obh);
    if (l < L_ - 1) {
      stage_kernel<false, false><<<M / 64, 384, 0, stream>>>(
          nullptr, nullptr, nullptr, nullptr, obh,
          P + OFF_PROJ + (size_t)l * 9216, b_proj + l * 96, x,
          P + OFF_FF1 + (size_t)l * 36864, b_ff1 + l * 384,
          P + OFF_FF2 + (size_t)l * 36864, b_ff2 + l * 96,
          ln2_g + l * 96, ln2_b + l * 96,
          ln1_g + (l + 1) * 96, ln1_b + (l + 1) * 96,
          P + OFF_QKV + (size_t)(l + 1) * 27648, nullptr, Qh, Kh, Vt, nullptr);
    } else {
      stage_kernel<false, true><<<M / 64, 384, 0, stream>>>(
          nullptr, nullptr, nullptr, nullptr, obh,
          P + OFF_PROJ + (size_t)l * 9216, b_proj + l * 96, x,
          P + OFF_FF1 + (size_t)l * 36864, b_ff1 + l * 384,
          P + OFF_FF2 + (size_t)l * 36864, b_ff2 + l * 96,
          ln2_g + l * 96, ln2_b + l * 96,
          lnf_g, lnf_b, P + OFF_ACT, b_act, nullptr, nullptr, nullptr, out);
    }
  }
}

// Round 18
// 213.198 us; speedup vs baseline: 1.4335x; 1.1372x over previous
//
#include <hip/hip_runtime.h>
#include <math.h>

#define B_ 16
#define T_ 1024
#define D_ 96
#define L_ 6
#define NH_ 6
#define HS_ 16
#define FF_ 384

typedef _Float16 h4 __attribute__((ext_vector_type(4)));
typedef _Float16 h8 __attribute__((ext_vector_type(8)));
typedef __fp16 g2 __attribute__((ext_vector_type(2)));
typedef __fp16 g4 __attribute__((ext_vector_type(4)));
typedef float f4 __attribute__((ext_vector_type(4)));

#define MFMA16 __builtin_amdgcn_mfma_f32_16x16x16f16

// packed f16 weights, layout [frag][stp][lane 0..63][8 halves]
#define OFF_GO   0
#define OFF_QKV  9216
#define OFF_PROJ 175104
#define OFF_FF1  230400
#define OFF_FF2  451584
#define OFF_ACT  672768
#define PACK_TOTAL 674304

// Q weights pre-scaled by 1/sqrt(16) * log2(e) so attn uses exp2 directly.
#define QSCALE 0.3606737602222409f

static __device__ __forceinline__ h4 pk4(const float* p) {
  g2 lo = __builtin_amdgcn_cvt_pkrtz(p[0], p[1]);
  g2 hi = __builtin_amdgcn_cvt_pkrtz(p[2], p[3]);
  g4 r4 = __builtin_shufflevector(lo, hi, 0, 1, 2, 3);
  return __builtin_bit_cast(h4, r4);
}

static __device__ __forceinline__ void ldpair(const _Float16* base, int blk,
                                              int lane, h4& a, h4& b) {
  h8 t = *(const h8*)(base + (size_t)blk * 512 + lane * 8);
  a = __builtin_shufflevector(t, t, 0, 1, 2, 3);
  b = __builtin_shufflevector(t, t, 4, 5, 6, 7);
}

// ---------- pack all weights into paired-fragment layout ----------
__global__ __launch_bounds__(256) void pack_all_kernel(
    const float* __restrict__ w_go, const float* __restrict__ wq,
    const float* __restrict__ wk, const float* __restrict__ wv,
    const float* __restrict__ w_proj, const float* __restrict__ w_ff1,
    const float* __restrict__ w_ff2, const float* __restrict__ w_act,
    _Float16* __restrict__ P) {
  int i = blockIdx.x * 256 + threadIdx.x;
  if (i >= PACK_TOTAL) return;
  float v;
  if (i < OFF_QKV) {                       // GO: 6 frags, 3 stp
    int o = i, nf = o / 1536, r = o % 1536, stp = r / 512, q = r & 511;
    int lane = q >> 3, h8i = q & 7, lr = lane & 15, lg = lane >> 4;
    int st = stp * 2 + (h8i >> 2), j = h8i & 3;
    int n = nf * 16 + lr, k = st * 16 + lg * 4 + j;
    v = w_go[k * 96 + n];
  } else if (i < OFF_PROJ) {               // QKV: per layer 18 frags, 3 stp
    int o = i - OFF_QKV, l = o / 27648, r0 = o % 27648;
    int nf = r0 / 1536, r = r0 % 1536, stp = r / 512, q = r & 511;
    int lane = q >> 3, h8i = q & 7, lr = lane & 15, lg = lane >> 4;
    int st = stp * 2 + (h8i >> 2), j = h8i & 3;
    int c = nf * 16 + lr, k = st * 16 + lg * 4 + j;
    int which = c / 96, hc = c % 96, h = hc >> 4, jx = hc & 15;
    const float* s = (which == 0) ? wq : (which == 1 ? wk : wv);
    v = s[((l * NH_ + h) * 96 + k) * 16 + jx];
    if (which == 0) v *= QSCALE;
  } else if (i < OFF_FF1) {                // PROJ: per layer 6 frags, 3 stp
    int o = i - OFF_PROJ, l = o / 9216, r0 = o % 9216;
    int nf = r0 / 1536, r = r0 % 1536, stp = r / 512, q = r & 511;
    int lane = q >> 3, h8i = q & 7, lr = lane & 15, lg = lane >> 4;
    int st = stp * 2 + (h8i >> 2), j = h8i & 3;
    int n = nf * 16 + lr, k = st * 16 + lg * 4 + j;
    v = w_proj[l * 9216 + k * 96 + n];
  } else if (i < OFF_FF2) {                // FF1: per layer 24 frags, 3 stp
    int o = i - OFF_FF1, l = o / 36864, r0 = o % 36864;
    int nf = r0 / 1536, r = r0 % 1536, stp = r / 512, q = r & 511;
    int lane = q >> 3, h8i = q & 7, lr = lane & 15, lg = lane >> 4;
    int st = stp * 2 + (h8i >> 2), j = h8i & 3;
    int n = nf * 16 + lr, k = st * 16 + lg * 4 + j;
    v = w_ff1[l * 36864 + k * 384 + n];
  } else if (i < OFF_ACT) {                // FF2: per layer 6 frags, 12 stp
    int o = i - OFF_FF2, l = o / 36864, r0 = o % 36864;
    int nf = r0 / 6144, r = r0 % 6144, stp = r / 512, q = r & 511;
    int lane = q >> 3, h8i = q & 7, lr = lane & 15, lg = lane >> 4;
    int st = stp * 2 + (h8i >> 2), j = h8i & 3;
    int n = nf * 16 + lr, k = st * 16 + lg * 4 + j;
    v = w_ff2[l * 36864 + k * 96 + n];
  } else {                                 // ACT: 1 frag, 3 stp
    int o = i - OFF_ACT, stp = o / 512, q = o & 511;
    int lane = q >> 3, h8i = q & 7, lr = lane & 15, lg = lane >> 4;
    int st = stp * 2 + (h8i >> 2), j = h8i & 3;
    int k = st * 16 + lg * 4 + j;
    v = w_act[k * 16 + lr];
  }
  P[i] = (_Float16)v;
}

// ---------- fused stage kernel: 6 waves x 4 token-groups (64 tokens) ------
// obp: attn-out paired [tb=tok/16][stp0..2][lane][8] (d pairs).
// Qp/Kp paired [bh][tile32][lane][8] (token-half pairs); Vp [bh][tile][lane][8]
// (s-half pairs, d=lane&15 rows).
template <bool EMBED, bool HEAD>
__global__ __launch_bounds__(384, 1) void stage_kernel(
    const float* __restrict__ goals, const float* __restrict__ obss,
    const float* __restrict__ pos, const float* __restrict__ b_go,
    const _Float16* __restrict__ obp, const _Float16* __restrict__ Wp,
    const float* __restrict__ bp, float* __restrict__ x,
    const _Float16* __restrict__ W1, const float* __restrict__ b1,
    const _Float16* __restrict__ W2, const float* __restrict__ b2,
    const float* __restrict__ ln2g, const float* __restrict__ ln2b,
    const float* __restrict__ lntg, const float* __restrict__ lntb,
    const _Float16* __restrict__ Wtail, const float* __restrict__ btail,
    _Float16* __restrict__ qp_, _Float16* __restrict__ kp_,
    _Float16* __restrict__ vp_, float* __restrict__ out) {
  __shared__ float smemf[16128];  // 64512 B
#define XSH(g, row, c) ((_Float16*)smemf + (size_t)(g) * 1920 + (row) * 20 + (c))
#define HSP(g, fp) ((_Float16*)smemf + ((size_t)(g) * 12 + (fp)) * 512)
#define LNS(g, w, r, i) smemf[15360 + (((g) * 6 + (w)) * 16 + (r)) * 2 + (i)]
  const int tid = threadIdx.x;
  const int wave = tid >> 6, lane = tid & 63;
  const int lr = lane & 15, lg = lane >> 4;
  const int row0 = blockIdx.x * 64;
  const int bidx = row0 >> 10;
  const int row0b = row0 & 1023;
  const int cfo = wave;  // owned col-frag 0..5
  const f4 zero4 = {0.f, 0.f, 0.f, 0.f};
  int tok[4], tt[4];
#pragma unroll
  for (int g = 0; g < 4; ++g) { tok[g] = row0 + g * 16 + lr; tt[g] = tok[g] & 1023; }

  f4 xc[4], x1[4];

  if constexpr (EMBED) {
    h4 ef[4][6];
#pragma unroll
    for (int st = 0; st < 2; ++st) {
      f4 s4 = *(const f4*)(goals + bidx * 32 + st * 16 + lg * 4);
      h4 e = (h4){(_Float16)s4[0], (_Float16)s4[1], (_Float16)s4[2], (_Float16)s4[3]};
#pragma unroll
      for (int g = 0; g < 4; ++g) ef[g][st] = e;
    }
#pragma unroll
    for (int g = 0; g < 4; ++g)
#pragma unroll
      for (int st = 2; st < 6; ++st) {
        f4 s4 = *(const f4*)(obss + (size_t)(bidx * 1024 + tt[g]) * 64 +
                             (st - 2) * 16 + lg * 4);
        ef[g][st] = (h4){(_Float16)s4[0], (_Float16)s4[1], (_Float16)s4[2], (_Float16)s4[3]};
      }
    h4 wf[6];
#pragma unroll
    for (int stp = 0; stp < 3; ++stp)
      ldpair(Wp, cfo * 3 + stp, lane, wf[2 * stp], wf[2 * stp + 1]);
    f4 bb = *(const f4*)(b_go + cfo * 16 + lg * 4);
#pragma unroll
    for (int g = 0; g < 4; ++g) {
      f4 a = zero4;
#pragma unroll
      for (int st = 0; st < 6; ++st) a = MFMA16(wf[st], ef[g][st], a, 0, 0, 0);
      f4 pp = *(const f4*)(pos + (size_t)tt[g] * 96 + cfo * 16 + lg * 4);
#pragma unroll
      for (int j = 0; j < 4; ++j) xc[g][j] = a[j] + bb[j] + pp[j];
      *(f4*)(x + (size_t)tok[g] * 96 + cfo * 16 + lg * 4) = xc[g];
    }
  } else {
    // ---- proj + resid: obf via paired h8 loads ----
    h4 obf[4][6];
#pragma unroll
    for (int g = 0; g < 4; ++g)
#pragma unroll
      for (int stp = 0; stp < 3; ++stp)
        ldpair(obp, (blockIdx.x * 4 + g) * 3 + stp, lane,
               obf[g][2 * stp], obf[g][2 * stp + 1]);
    h4 wf[6];
#pragma unroll
    for (int stp = 0; stp < 3; ++stp)
      ldpair(Wp, cfo * 3 + stp, lane, wf[2 * stp], wf[2 * stp + 1]);
    f4 bb = *(const f4*)(bp + cfo * 16 + lg * 4);
#pragma unroll
    for (int g = 0; g < 4; ++g) {
      f4 a = zero4;
#pragma unroll
      for (int st = 0; st < 6; ++st) a = MFMA16(wf[st], obf[g][st], a, 0, 0, 0);
      f4 xr = *(const f4*)(x + (size_t)tok[g] * 96 + cfo * 16 + lg * 4);
#pragma unroll
      for (int j = 0; j < 4; ++j) x1[g][j] = a[j] + bb[j] + xr[j];
    }
    // ---- LN2 partials ----
#pragma unroll
    for (int g = 0; g < 4; ++g) {
      float s = x1[g][0] + x1[g][1] + x1[g][2] + x1[g][3];
      float sq = x1[g][0] * x1[g][0] + x1[g][1] * x1[g][1] +
                 x1[g][2] * x1[g][2] + x1[g][3] * x1[g][3];
      s += __shfl_xor(s, 16); sq += __shfl_xor(sq, 16);
      s += __shfl_xor(s, 32); sq += __shfl_xor(sq, 32);
      if (lane < 16) { LNS(g, wave, lr, 0) = s; LNS(g, wave, lr, 1) = sq; }
    }
    __syncthreads();  // B1
    {
      f4 gg4 = *(const f4*)(ln2g + cfo * 16 + lg * 4);
      f4 b4 = *(const f4*)(ln2b + cfo * 16 + lg * 4);
#pragma unroll
      for (int g = 0; g < 4; ++g) {
        float s = 0.f, sq = 0.f;
#pragma unroll
        for (int w = 0; w < 6; ++w) { s += LNS(g, w, lr, 0); sq += LNS(g, w, lr, 1); }
        float mean = s * (1.f / 96.f);
        float rs = rsqrtf(sq * (1.f / 96.f) - mean * mean + 1e-5f);
        h4 xn;
#pragma unroll
        for (int j = 0; j < 4; ++j)
          xn[j] = (_Float16)((x1[g][j] - mean) * rs * gg4[j] + b4[j]);
        *(h4*)XSH(g, cfo * 16 + lr, lg * 4) = xn;
      }
    }
    __syncthreads();  // B2
    h4 xnf[4][6];
#pragma unroll
    for (int g = 0; g < 4; ++g)
#pragma unroll
      for (int st = 0; st < 6; ++st)
        xnf[g][st] = *(const h4*)XSH(g, st * 16 + lr, lg * 4);
    __syncthreads();  // B2b (xn fully read before HSP overlays it)

    // ---- ff1 + relu -> HSP pairs (own 4 hidden frags = 2 pairs) ----
#pragma unroll
    for (int p = 0; p < 2; ++p) {
      int nf0 = wave * 4 + p * 2;
      h4 wA[6], wB[6];
#pragma unroll
      for (int stp = 0; stp < 3; ++stp) {
        ldpair(W1, nf0 * 3 + stp, lane, wA[2 * stp], wA[2 * stp + 1]);
        ldpair(W1, (nf0 + 1) * 3 + stp, lane, wB[2 * stp], wB[2 * stp + 1]);
      }
      f4 bA = *(const f4*)(b1 + nf0 * 16 + lg * 4);
      f4 bB = *(const f4*)(b1 + (nf0 + 1) * 16 + lg * 4);
#pragma unroll
      for (int g = 0; g < 4; ++g) {
        f4 hA = zero4, hB = zero4;
#pragma unroll
        for (int st = 0; st < 6; ++st) {
          hA = MFMA16(wA[st], xnf[g][st], hA, 0, 0, 0);
          hB = MFMA16(wB[st], xnf[g][st], hB, 0, 0, 0);
        }
        h4 lo, hi;
#pragma unroll
        for (int j = 0; j < 4; ++j) {
          lo[j] = (_Float16)fmaxf(hA[j] + bA[j], 0.f);
          hi[j] = (_Float16)fmaxf(hB[j] + bB[j], 0.f);
        }
        h8 comb = __builtin_shufflevector(lo, hi, 0, 1, 2, 3, 4, 5, 6, 7);
        *(h8*)(HSP(g, wave * 2 + p) + lane * 8) = comb;
      }
    }
    // ---- ff2 (own 1 output frag, full K=384 from HSP pairs) ----
    h4 w2f[24];
#pragma unroll
    for (int stp = 0; stp < 12; ++stp)
      ldpair(W2, cfo * 12 + stp, lane, w2f[2 * stp], w2f[2 * stp + 1]);
    __syncthreads();  // B3 (all hf written)
    {
      f4 b4 = *(const f4*)(b2 + cfo * 16 + lg * 4);
#pragma unroll
      for (int g = 0; g < 4; ++g) {
        f4 y = zero4;
#pragma unroll
        for (int fp = 0; fp < 12; ++fp) {
          h8 t = *(const h8*)(HSP(g, fp) + lane * 8);
          h4 lo = __builtin_shufflevector(t, t, 0, 1, 2, 3);
          h4 hi = __builtin_shufflevector(t, t, 4, 5, 6, 7);
          y = MFMA16(w2f[2 * fp], lo, y, 0, 0, 0);
          y = MFMA16(w2f[2 * fp + 1], hi, y, 0, 0, 0);
        }
#pragma unroll
        for (int j = 0; j < 4; ++j) xc[g][j] = x1[g][j] + y[j] + b4[j];
        if constexpr (!HEAD)
          *(f4*)(x + (size_t)tok[g] * 96 + cfo * 16 + lg * 4) = xc[g];
      }
    }
  }

  // ---- tail LN on xc ----
#pragma unroll
  for (int g = 0; g < 4; ++g) {
    float s = xc[g][0] + xc[g][1] + xc[g][2] + xc[g][3];
    float sq = xc[g][0] * xc[g][0] + xc[g][1] * xc[g][1] +
               xc[g][2] * xc[g][2] + xc[g][3] * xc[g][3];
    s += __shfl_xor(s, 16); sq += __shfl_xor(sq, 16);
    s += __shfl_xor(s, 32); sq += __shfl_xor(sq, 32);
    if (lane < 16) { LNS(g, wave, lr, 0) = s; LNS(g, wave, lr, 1) = sq; }
  }
  __syncthreads();  // B4 (all HSP reads done before XSH overlays)
  {
    f4 gg4 = *(const f4*)(lntg + cfo * 16 + lg * 4);
    f4 b4 = *(const f4*)(lntb + cfo * 16 + lg * 4);
#pragma unroll
    for (int g = 0; g < 4; ++g) {
      float s = 0.f, sq = 0.f;
#pragma unroll
      for (int w = 0; w < 6; ++w) { s += LNS(g, w, lr, 0); sq += LNS(g, w, lr, 1); }
      float mean = s * (1.f / 96.f);
      float rs = rsqrtf(sq * (1.f / 96.f) - mean * mean + 1e-5f);
      h4 xn;
#pragma unroll
      for (int j = 0; j < 4; ++j)
        xn[j] = (_Float16)((xc[g][j] - mean) * rs * gg4[j] + b4[j]);
      *(h4*)XSH(g, cfo * 16 + lr, lg * 4) = xn;
    }
  }
  __syncthreads();  // B5
  if constexpr (HEAD) {
    if (wave == 0) {
      h4 wt[6];
#pragma unroll
      for (int stp = 0; stp < 3; ++stp)
        ldpair(Wtail, stp, lane, wt[2 * stp], wt[2 * stp + 1]);
      f4 bb = *(const f4*)(btail + lg * 4);
#pragma unroll
      for (int g = 0; g < 4; ++g) {
        f4 a = zero4;
#pragma unroll
        for (int st = 0; st < 6; ++st) {
          h4 xf = *(const h4*)XSH(g, st * 16 + lr, lg * 4);
          a = MFMA16(wt[st], xf, a, 0, 0, 0);
        }
        f4 o;
#pragma unroll
        for (int j = 0; j < 4; ++j) o[j] = a[j] + bb[j];
        *(f4*)(out + (size_t)tok[g] * 16 + lg * 4) = o;
      }
    }
  } else {
    h4 xf[4][6];
#pragma unroll
    for (int g = 0; g < 4; ++g)
#pragma unroll
      for (int st = 0; st < 6; ++st)
        xf[g][st] = *(const h4*)XSH(g, st * 16 + lr, lg * 4);
    // tail frags: nf = wave*3 + f; Q:0-5 K:6-11 V:12-17
#pragma unroll
    for (int f = 0; f < 3; ++f) {
      int nf = wave * 3 + f;
      h4 wt[6];
#pragma unroll
      for (int stp = 0; stp < 3; ++stp)
        ldpair(Wtail, nf * 3 + stp, lane, wt[2 * stp], wt[2 * stp + 1]);
#pragma unroll
      for (int g = 0; g < 4; ++g) {
        int t2 = (row0b >> 5) + (g >> 1);
        f4 a = zero4;
#pragma unroll
        for (int st = 0; st < 6; ++st) a = MFMA16(wt[st], xf[g][st], a, 0, 0, 0);
        if (nf < 12) {  // Q or K paired tile: h4 at [lane][(g&1)*4]
          int h = nf < 6 ? nf : nf - 6;
          _Float16* dst = (nf < 6 ? qp_ : kp_) +
                          ((size_t)(bidx * NH_ + h) * 32 + t2) * 512 +
                          lane * 8 + (g & 1) * 4;
          h4 hv = {(_Float16)a[0], (_Float16)a[1], (_Float16)a[2], (_Float16)a[3]};
          *(h4*)dst = hv;
        } else {        // V paired tile: scalar scatter per r
          int hb = nf - 12;
          _Float16* vbase = vp_ + ((size_t)(bidx * NH_ + hb) * 32 + t2) * 512;
          int jb = (lr & 3) + (g & 1) * 4;
          int lgp = lr >> 2;
#pragma unroll
          for (int r = 0; r < 4; ++r)
            vbase[(lgp * 16 + lg * 4 + r) * 8 + jb] = (_Float16)a[r];
        }
      }
    }
  }
#undef XSH
#undef HSP
#undef LNS
}

// ---------- MFMA f16 flash attention: 32 q-rows/wave, paired tile loads ----
__global__ __launch_bounds__(256, 6) void attn_mfma_kernel(
    const _Float16* __restrict__ Qp, const _Float16* __restrict__ Kp,
    const _Float16* __restrict__ Vp, _Float16* __restrict__ obp) {
  int bh = blockIdx.x;
  int wave = threadIdx.x >> 6;
  int lane = threadIdx.x & 63;
  int qb = wave * 8 + blockIdx.y;    // 0..31
  int lr = lane & 15;
  int lg = lane >> 4;

  const _Float16* qB = Qp + (size_t)bh * 16384;
  const _Float16* kB = Kp + (size_t)bh * 16384;
  const _Float16* vB = Vp + (size_t)bh * 16384;

  h4 qf0, qf1;
  {
    h8 t = *(const h8*)(qB + (size_t)qb * 512 + lane * 8);
    qf0 = __builtin_shufflevector(t, t, 0, 1, 2, 3);
    qf1 = __builtin_shufflevector(t, t, 4, 5, 6, 7);
  }
  f4 O0 = {0.f, 0.f, 0.f, 0.f}, O1 = {0.f, 0.f, 0.f, 0.f};
  f4 S0 = {0.f, 0.f, 0.f, 0.f}, S1 = {0.f, 0.f, 0.f, 0.f};
  const f4 zero4 = {0.f, 0.f, 0.f, 0.f};
  const h4 ones = {(_Float16)1.f, (_Float16)1.f, (_Float16)1.f, (_Float16)1.f};

  h4 kc0, kc1, vc0, vc1, kn0, kn1, vn0, vn1;
  {
    h8 kt = *(const h8*)(kB + lane * 8);
    kc0 = __builtin_shufflevector(kt, kt, 0, 1, 2, 3);
    kc1 = __builtin_shufflevector(kt, kt, 4, 5, 6, 7);
    h8 vt8 = *(const h8*)(vB + lane * 8);
    vc0 = __builtin_shufflevector(vt8, vt8, 0, 1, 2, 3);
    vc1 = __builtin_shufflevector(vt8, vt8, 4, 5, 6, 7);
  }

  for (int tt = 0; tt < qb; ++tt) {
    {
      h8 kt = *(const h8*)(kB + (size_t)(tt + 1) * 512 + lane * 8);
      kn0 = __builtin_shufflevector(kt, kt, 0, 1, 2, 3);
      kn1 = __builtin_shufflevector(kt, kt, 4, 5, 6, 7);
      h8 vt8 = *(const h8*)(vB + (size_t)(tt + 1) * 512 + lane * 8);
      vn0 = __builtin_shufflevector(vt8, vt8, 0, 1, 2, 3);
      vn1 = __builtin_shufflevector(vt8, vt8, 4, 5, 6, 7);
    }
    f4 sa0 = MFMA16(kc0, qf0, zero4, 0, 0, 0);
    f4 sa1 = MFMA16(kc1, qf0, zero4, 0, 0, 0);
    f4 sb0 = MFMA16(kc0, qf1, zero4, 0, 0, 0);
    f4 sb1 = MFMA16(kc1, qf1, zero4, 0, 0, 0);
    float pa0[4], pa1[4], pb0[4], pb1[4];
#pragma unroll
    for (int r = 0; r < 4; ++r) {
      pa0[r] = __builtin_amdgcn_exp2f(sa0[r]);
      pa1[r] = __builtin_amdgcn_exp2f(sa1[r]);
      pb0[r] = __builtin_amdgcn_exp2f(sb0[r]);
      pb1[r] = __builtin_amdgcn_exp2f(sb1[r]);
    }
    h4 fa0 = pk4(pa0), fa1 = pk4(pa1), fb0 = pk4(pb0), fb1 = pk4(pb1);
    O0 = MFMA16(fa0, vc0, O0, 0, 0, 0);
    O0 = MFMA16(fa1, vc1, O0, 0, 0, 0);
    S0 = MFMA16(fa0, ones, S0, 0, 0, 0);
    S0 = MFMA16(fa1, ones, S0, 0, 0, 0);
    O1 = MFMA16(fb0, vc0, O1, 0, 0, 0);
    O1 = MFMA16(fb1, vc1, O1, 0, 0, 0);
    S1 = MFMA16(fb0, ones, S1, 0, 0, 0);
    S1 = MFMA16(fb1, ones, S1, 0, 0, 0);
    kc0 = kn0; kc1 = kn1; vc0 = vn0; vc1 = vn1;
  }

  {
    f4 sa0 = MFMA16(kc0, qf0, zero4, 0, 0, 0);
    float pa0[4];
#pragma unroll
    for (int r = 0; r < 4; ++r)
      pa0[r] = (lg * 4 + r <= lr) ? __builtin_amdgcn_exp2f(sa0[r]) : 0.f;
    h4 fa0 = pk4(pa0);
    O0 = MFMA16(fa0, vc0, O0, 0, 0, 0);
    S0 = MFMA16(fa0, ones, S0, 0, 0, 0);

    f4 sb0 = MFMA16(kc0, qf1, zero4, 0, 0, 0);
    f4 sb1 = MFMA16(kc1, qf1, zero4, 0, 0, 0);
    float pb0[4], pb1[4];
#pragma unroll
    for (int r = 0; r < 4; ++r) {
      pb0[r] = __builtin_amdgcn_exp2f(sb0[r]);
      pb1[r] = (lg * 4 + r <= lr) ? __builtin_amdgcn_exp2f(sb1[r]) : 0.f;
    }
    h4 fb0 = pk4(pb0), fb1 = pk4(pb1);
    O1 = MFMA16(fb0, vc0, O1, 0, 0, 0);
    O1 = MFMA16(fb1, vc1, O1, 0, 0, 0);
    S1 = MFMA16(fb0, ones, S1, 0, 0, 0);
    S1 = MFMA16(fb1, ones, S1, 0, 0, 0);
  }

  // write obp: token tb = b*64 + qb*2 + u; lr' = lg*4+r; stp = h>>1;
  // lg'' = lr>>2; j = (lr&3) + (h&1)*4.
  int b = bh / NH_, h = bh % NH_;
  int stp = h >> 1;
  int jb = (lr & 3) + (h & 1) * 4;
  int lgp = lr >> 2;
  size_t tb0 = (size_t)b * 64 + qb * 2;
#pragma unroll
  for (int r = 0; r < 4; ++r) {
    float li0 = __builtin_amdgcn_rcpf(S0[r]);
    float li1 = __builtin_amdgcn_rcpf(S1[r]);
    size_t pos = (size_t)(lgp * 16 + lg * 4 + r) * 8 + jb;
    obp[(tb0 * 3 + stp) * 512 + pos] = (_Float16)(O0[r] * li0);
    obp[((tb0 + 1) * 3 + stp) * 512 + pos] = (_Float16)(O1[r] * li1);
  }
}

extern "C" void kernel_launch(void* const* d_in, const int* in_sizes, int n_in,
                              void* d_out, int out_size, void* d_ws, size_t ws_size,
                              hipStream_t stream) {
  const float* goals   = (const float*)d_in[0];
  const float* obss    = (const float*)d_in[1];
  const float* w_go    = (const float*)d_in[2];
  const float* b_go    = (const float*)d_in[3];
  const float* pos_emb = (const float*)d_in[4];
  const float* wq      = (const float*)d_in[5];
  const float* wk      = (const float*)d_in[6];
  const float* wv      = (const float*)d_in[7];
  const float* w_proj  = (const float*)d_in[8];
  const float* b_proj  = (const float*)d_in[9];
  const float* ln1_g   = (const float*)d_in[10];
  const float* ln1_b   = (const float*)d_in[11];
  const float* ln2_g   = (const float*)d_in[12];
  const float* ln2_b   = (const float*)d_in[13];
  const float* w_ff1   = (const float*)d_in[14];
  const float* b_ff1   = (const float*)d_in[15];
  const float* w_ff2   = (const float*)d_in[16];
  const float* b_ff2   = (const float*)d_in[17];
  const float* lnf_g   = (const float*)d_in[18];
  const float* lnf_b   = (const float*)d_in[19];
  const float* w_act   = (const float*)d_in[20];
  const float* b_act   = (const float*)d_in[21];
  float* out = (float*)d_out;

  const int M = B_ * T_;  // 16384
  float* ws = (float*)d_ws;
  size_t off = 0;
  _Float16* P = (_Float16*)(ws + off); off += PACK_TOTAL / 2 + 64;
  float* x = ws + off; off += (size_t)M * 96;
  _Float16* obp = (_Float16*)(ws + off); off += (size_t)M * 48;
  _Float16* Qp = (_Float16*)(ws + off); off += (size_t)M * 48;
  _Float16* Kp = (_Float16*)(ws + off); off += (size_t)M * 48;
  _Float16* Vp = (_Float16*)(ws + off); off += (size_t)M * 48;

  pack_all_kernel<<<(PACK_TOTAL + 255) / 256, 256, 0, stream>>>(
      w_go, wq, wk, wv, w_proj, w_ff1, w_ff2, w_act, P);

  // embed + qkv(layer 0)
  stage_kernel<true, false><<<M / 64, 384, 0, stream>>>(
      goals, obss, pos_emb, b_go, nullptr, P + OFF_GO, nullptr, x,
      nullptr, nullptr, nullptr, nullptr, nullptr, nullptr,
      ln1_g, ln1_b, P + OFF_QKV, nullptr, Qp, Kp, Vp, nullptr);

  for (int l = 0; l < L_; ++l) {
    attn_mfma_kernel<<<dim3(B_ * NH_, 8), 256, 0, stream>>>(Qp, Kp, Vp, obp);
    if (l < L_ - 1) {
      stage_kernel<false, false><<<M / 64, 384, 0, stream>>>(
          nullptr, nullptr, nullptr, nullptr, obp,
          P + OFF_PROJ + (size_t)l * 9216, b_proj + l * 96, x,
          P + OFF_FF1 + (size_t)l * 36864, b_ff1 + l * 384,
          P + OFF_FF2 + (size_t)l * 36864, b_ff2 + l * 96,
          ln2_g + l * 96, ln2_b + l * 96,
          ln1_g + (l + 1) * 96, ln1_b + (l + 1) * 96,
          P + OFF_QKV + (size_t)(l + 1) * 27648, nullptr, Qp, Kp, Vp, nullptr);
    } else {
      stage_kernel<false, true><<<M / 64, 384, 0, stream>>>(
          nullptr, nullptr, nullptr, nullptr, obp,
          P + OFF_PROJ + (size_t)l * 9216, b_proj + l * 96, x,
          P + OFF_FF1 + (size_t)l * 36864, b_ff1 + l * 384,
          P + OFF_FF2 + (size_t)l * 36864, b_ff2 + l * 96,
          ln2_g + l * 96, ln2_b + l * 96,
          lnf_g, lnf_b, P + OFF_ACT, b_act, nullptr, nullptr, nullptr, out);
    }
  }
}

// Round 19
// 210.929 us; speedup vs baseline: 1.4490x; 1.0108x over previous
//
#include <hip/hip_runtime.h>
#include <math.h>

#define B_ 16
#define T_ 1024
#define D_ 96
#define L_ 6
#define NH_ 6
#define HS_ 16
#define FF_ 384

typedef _Float16 h4 __attribute__((ext_vector_type(4)));
typedef _Float16 h8 __attribute__((ext_vector_type(8)));
typedef __fp16 g2 __attribute__((ext_vector_type(2)));
typedef __fp16 g4 __attribute__((ext_vector_type(4)));
typedef float f4 __attribute__((ext_vector_type(4)));

#define MFMA16 __builtin_amdgcn_mfma_f32_16x16x16f16

// packed f16 weights, layout [frag][stp][lane 0..63][8 halves]
#define OFF_GO   0
#define OFF_QKV  9216
#define OFF_PROJ 175104
#define OFF_FF1  230400
#define OFF_FF2  451584
#define OFF_ACT  672768
#define PACK_TOTAL 674304

// Q weights pre-scaled by 1/sqrt(16) * log2(e) so attn uses exp2 directly.
#define QSCALE 0.3606737602222409f

static __device__ __forceinline__ h4 pk4(const float* p) {
  g2 lo = __builtin_amdgcn_cvt_pkrtz(p[0], p[1]);
  g2 hi = __builtin_amdgcn_cvt_pkrtz(p[2], p[3]);
  g4 r4 = __builtin_shufflevector(lo, hi, 0, 1, 2, 3);
  return __builtin_bit_cast(h4, r4);
}

static __device__ __forceinline__ void ldpair(const _Float16* base, int blk,
                                              int lane, h4& a, h4& b) {
  h8 t = *(const h8*)(base + (size_t)blk * 512 + lane * 8);
  a = __builtin_shufflevector(t, t, 0, 1, 2, 3);
  b = __builtin_shufflevector(t, t, 4, 5, 6, 7);
}

// ---------- pack all weights into paired-fragment layout ----------
__global__ __launch_bounds__(256) void pack_all_kernel(
    const float* __restrict__ w_go, const float* __restrict__ wq,
    const float* __restrict__ wk, const float* __restrict__ wv,
    const float* __restrict__ w_proj, const float* __restrict__ w_ff1,
    const float* __restrict__ w_ff2, const float* __restrict__ w_act,
    _Float16* __restrict__ P) {
  int i = blockIdx.x * 256 + threadIdx.x;
  if (i >= PACK_TOTAL) return;
  float v;
  if (i < OFF_QKV) {                       // GO: 6 frags, 3 stp
    int o = i, nf = o / 1536, r = o % 1536, stp = r / 512, q = r & 511;
    int lane = q >> 3, h8i = q & 7, lr = lane & 15, lg = lane >> 4;
    int st = stp * 2 + (h8i >> 2), j = h8i & 3;
    int n = nf * 16 + lr, k = st * 16 + lg * 4 + j;
    v = w_go[k * 96 + n];
  } else if (i < OFF_PROJ) {               // QKV: per layer 18 frags, 3 stp
    int o = i - OFF_QKV, l = o / 27648, r0 = o % 27648;
    int nf = r0 / 1536, r = r0 % 1536, stp = r / 512, q = r & 511;
    int lane = q >> 3, h8i = q & 7, lr = lane & 15, lg = lane >> 4;
    int st = stp * 2 + (h8i >> 2), j = h8i & 3;
    int c = nf * 16 + lr, k = st * 16 + lg * 4 + j;
    int which = c / 96, hc = c % 96, h = hc >> 4, jx = hc & 15;
    const float* s = (which == 0) ? wq : (which == 1 ? wk : wv);
    v = s[((l * NH_ + h) * 96 + k) * 16 + jx];
    if (which == 0) v *= QSCALE;
  } else if (i < OFF_FF1) {                // PROJ: per layer 6 frags, 3 stp
    int o = i - OFF_PROJ, l = o / 9216, r0 = o % 9216;
    int nf = r0 / 1536, r = r0 % 1536, stp = r / 512, q = r & 511;
    int lane = q >> 3, h8i = q & 7, lr = lane & 15, lg = lane >> 4;
    int st = stp * 2 + (h8i >> 2), j = h8i & 3;
    int n = nf * 16 + lr, k = st * 16 + lg * 4 + j;
    v = w_proj[l * 9216 + k * 96 + n];
  } else if (i < OFF_FF2) {                // FF1: per layer 24 frags, 3 stp
    int o = i - OFF_FF1, l = o / 36864, r0 = o % 36864;
    int nf = r0 / 1536, r = r0 % 1536, stp = r / 512, q = r & 511;
    int lane = q >> 3, h8i = q & 7, lr = lane & 15, lg = lane >> 4;
    int st = stp * 2 + (h8i >> 2), j = h8i & 3;
    int n = nf * 16 + lr, k = st * 16 + lg * 4 + j;
    v = w_ff1[l * 36864 + k * 384 + n];
  } else if (i < OFF_ACT) {                // FF2: per layer 6 frags, 12 stp
    int o = i - OFF_FF2, l = o / 36864, r0 = o % 36864;
    int nf = r0 / 6144, r = r0 % 6144, stp = r / 512, q = r & 511;
    int lane = q >> 3, h8i = q & 7, lr = lane & 15, lg = lane >> 4;
    int st = stp * 2 + (h8i >> 2), j = h8i & 3;
    int n = nf * 16 + lr, k = st * 16 + lg * 4 + j;
    v = w_ff2[l * 36864 + k * 96 + n];
  } else {                                 // ACT: 1 frag, 3 stp
    int o = i - OFF_ACT, stp = o / 512, q = o & 511;
    int lane = q >> 3, h8i = q & 7, lr = lane & 15, lg = lane >> 4;
    int st = stp * 2 + (h8i >> 2), j = h8i & 3;
    int k = st * 16 + lg * 4 + j;
    v = w_act[k * 16 + lr];
  }
  P[i] = (_Float16)v;
}

// ---------- fused stage kernel: 6 waves x 4 token-groups (64 tokens) ------
// obp: attn-out paired [tb][stp][lane][8]. Qp/Kp paired [bh][tile32][lane][8];
// Vp [bh][tile][lane][8]. x residual paired fp32 [tb][cf][lane][4].
template <bool EMBED, bool HEAD>
__global__ __launch_bounds__(384, 1) void stage_kernel(
    const float* __restrict__ goals, const float* __restrict__ obss,
    const float* __restrict__ pos, const float* __restrict__ b_go,
    const _Float16* __restrict__ obp, const _Float16* __restrict__ Wp,
    const float* __restrict__ bp, float* __restrict__ x,
    const _Float16* __restrict__ W1, const float* __restrict__ b1,
    const _Float16* __restrict__ W2, const float* __restrict__ b2,
    const float* __restrict__ ln2g, const float* __restrict__ ln2b,
    const float* __restrict__ lntg, const float* __restrict__ lntb,
    const _Float16* __restrict__ Wtail, const float* __restrict__ btail,
    _Float16* __restrict__ qp_, _Float16* __restrict__ kp_,
    _Float16* __restrict__ vp_, float* __restrict__ out) {
  __shared__ float smemf[16128];  // 64512 B
#define XSH(g, row, c) ((_Float16*)smemf + (size_t)(g) * 1920 + (row) * 20 + (c))
#define HSP(g, fp) ((_Float16*)smemf + ((size_t)(g) * 12 + (fp)) * 512)
#define LNS(g, w, r, i) smemf[15360 + (((g) * 6 + (w)) * 16 + (r)) * 2 + (i)]
#define XP(g) (x + ((size_t)(blockIdx.x * 4 + (g)) * 6 + cfo) * 256 + lane * 4)
  const int tid = threadIdx.x;
  const int wave = tid >> 6, lane = tid & 63;
  const int lr = lane & 15, lg = lane >> 4;
  const int row0 = blockIdx.x * 64;
  const int bidx = row0 >> 10;
  const int row0b = row0 & 1023;
  const int cfo = wave;  // owned col-frag 0..5
  const f4 zero4 = {0.f, 0.f, 0.f, 0.f};
  int tok[4], tt[4];
#pragma unroll
  for (int g = 0; g < 4; ++g) { tok[g] = row0 + g * 16 + lr; tt[g] = tok[g] & 1023; }

  f4 xc[4], x1[4];

  if constexpr (EMBED) {
    h4 ef[4][6];
#pragma unroll
    for (int st = 0; st < 2; ++st) {
      f4 s4 = *(const f4*)(goals + bidx * 32 + st * 16 + lg * 4);
      h4 e = (h4){(_Float16)s4[0], (_Float16)s4[1], (_Float16)s4[2], (_Float16)s4[3]};
#pragma unroll
      for (int g = 0; g < 4; ++g) ef[g][st] = e;
    }
#pragma unroll
    for (int g = 0; g < 4; ++g)
#pragma unroll
      for (int st = 2; st < 6; ++st) {
        f4 s4 = *(const f4*)(obss + (size_t)(bidx * 1024 + tt[g]) * 64 +
                             (st - 2) * 16 + lg * 4);
        ef[g][st] = (h4){(_Float16)s4[0], (_Float16)s4[1], (_Float16)s4[2], (_Float16)s4[3]};
      }
    h4 wf[6];
#pragma unroll
    for (int stp = 0; stp < 3; ++stp)
      ldpair(Wp, cfo * 3 + stp, lane, wf[2 * stp], wf[2 * stp + 1]);
    f4 bb = *(const f4*)(b_go + cfo * 16 + lg * 4);
#pragma unroll
    for (int g = 0; g < 4; ++g) {
      f4 a = zero4;
#pragma unroll
      for (int st = 0; st < 6; ++st) a = MFMA16(wf[st], ef[g][st], a, 0, 0, 0);
      f4 pp = *(const f4*)(pos + (size_t)tt[g] * 96 + cfo * 16 + lg * 4);
#pragma unroll
      for (int j = 0; j < 4; ++j) xc[g][j] = a[j] + bb[j] + pp[j];
      *(f4*)XP(g) = xc[g];
    }
  } else {
    // ---- proj + resid: obf via paired h8 loads ----
    h4 obf[4][6];
#pragma unroll
    for (int g = 0; g < 4; ++g)
#pragma unroll
      for (int stp = 0; stp < 3; ++stp)
        ldpair(obp, (blockIdx.x * 4 + g) * 3 + stp, lane,
               obf[g][2 * stp], obf[g][2 * stp + 1]);
    h4 wf[6];
#pragma unroll
    for (int stp = 0; stp < 3; ++stp)
      ldpair(Wp, cfo * 3 + stp, lane, wf[2 * stp], wf[2 * stp + 1]);
    f4 bb = *(const f4*)(bp + cfo * 16 + lg * 4);
#pragma unroll
    for (int g = 0; g < 4; ++g) {
      f4 a = zero4;
#pragma unroll
      for (int st = 0; st < 6; ++st) a = MFMA16(wf[st], obf[g][st], a, 0, 0, 0);
      f4 xr = *(const f4*)XP(g);
#pragma unroll
      for (int j = 0; j < 4; ++j) x1[g][j] = a[j] + bb[j] + xr[j];
    }
    // ---- LN2 partials ----
#pragma unroll
    for (int g = 0; g < 4; ++g) {
      float s = x1[g][0] + x1[g][1] + x1[g][2] + x1[g][3];
      float sq = x1[g][0] * x1[g][0] + x1[g][1] * x1[g][1] +
                 x1[g][2] * x1[g][2] + x1[g][3] * x1[g][3];
      s += __shfl_xor(s, 16); sq += __shfl_xor(sq, 16);
      s += __shfl_xor(s, 32); sq += __shfl_xor(sq, 32);
      if (lane < 16) { LNS(g, wave, lr, 0) = s; LNS(g, wave, lr, 1) = sq; }
    }
    __syncthreads();  // B1
    {
      f4 gg4 = *(const f4*)(ln2g + cfo * 16 + lg * 4);
      f4 b4 = *(const f4*)(ln2b + cfo * 16 + lg * 4);
#pragma unroll
      for (int g = 0; g < 4; ++g) {
        float s = 0.f, sq = 0.f;
#pragma unroll
        for (int w = 0; w < 6; ++w) { s += LNS(g, w, lr, 0); sq += LNS(g, w, lr, 1); }
        float mean = s * (1.f / 96.f);
        float rs = rsqrtf(sq * (1.f / 96.f) - mean * mean + 1e-5f);
        h4 xn;
#pragma unroll
        for (int j = 0; j < 4; ++j)
          xn[j] = (_Float16)((x1[g][j] - mean) * rs * gg4[j] + b4[j]);
        *(h4*)XSH(g, cfo * 16 + lr, lg * 4) = xn;
      }
    }
    __syncthreads();  // B2
    h4 xnf[4][6];
#pragma unroll
    for (int g = 0; g < 4; ++g)
#pragma unroll
      for (int st = 0; st < 6; ++st)
        xnf[g][st] = *(const h4*)XSH(g, st * 16 + lr, lg * 4);
    __syncthreads();  // B2b (xn fully read before HSP overlays it)

    // ---- ff1 + relu -> HSP pairs (own 4 hidden frags = 2 pairs) ----
#pragma unroll
    for (int p = 0; p < 2; ++p) {
      int nf0 = wave * 4 + p * 2;
      h4 wA[6], wB[6];
#pragma unroll
      for (int stp = 0; stp < 3; ++stp) {
        ldpair(W1, nf0 * 3 + stp, lane, wA[2 * stp], wA[2 * stp + 1]);
        ldpair(W1, (nf0 + 1) * 3 + stp, lane, wB[2 * stp], wB[2 * stp + 1]);
      }
      f4 bA = *(const f4*)(b1 + nf0 * 16 + lg * 4);
      f4 bB = *(const f4*)(b1 + (nf0 + 1) * 16 + lg * 4);
#pragma unroll
      for (int g = 0; g < 4; ++g) {
        f4 hA = zero4, hB = zero4;
#pragma unroll
        for (int st = 0; st < 6; ++st) {
          hA = MFMA16(wA[st], xnf[g][st], hA, 0, 0, 0);
          hB = MFMA16(wB[st], xnf[g][st], hB, 0, 0, 0);
        }
        h4 lo, hi;
#pragma unroll
        for (int j = 0; j < 4; ++j) {
          lo[j] = (_Float16)fmaxf(hA[j] + bA[j], 0.f);
          hi[j] = (_Float16)fmaxf(hB[j] + bB[j], 0.f);
        }
        h8 comb = __builtin_shufflevector(lo, hi, 0, 1, 2, 3, 4, 5, 6, 7);
        *(h8*)(HSP(g, wave * 2 + p) + lane * 8) = comb;
      }
    }
    // ---- ff2 (own 1 output frag, full K=384 from HSP pairs) ----
    h4 w2f[24];
#pragma unroll
    for (int stp = 0; stp < 12; ++stp)
      ldpair(W2, cfo * 12 + stp, lane, w2f[2 * stp], w2f[2 * stp + 1]);
    __syncthreads();  // B3 (all hf written)
    {
      f4 b4 = *(const f4*)(b2 + cfo * 16 + lg * 4);
#pragma unroll
      for (int g = 0; g < 4; ++g) {
        f4 y = zero4;
#pragma unroll
        for (int fp = 0; fp < 12; ++fp) {
          h8 t = *(const h8*)(HSP(g, fp) + lane * 8);
          h4 lo = __builtin_shufflevector(t, t, 0, 1, 2, 3);
          h4 hi = __builtin_shufflevector(t, t, 4, 5, 6, 7);
          y = MFMA16(w2f[2 * fp], lo, y, 0, 0, 0);
          y = MFMA16(w2f[2 * fp + 1], hi, y, 0, 0, 0);
        }
#pragma unroll
        for (int j = 0; j < 4; ++j) xc[g][j] = x1[g][j] + y[j] + b4[j];
        if constexpr (!HEAD)
          *(f4*)XP(g) = xc[g];
      }
    }
  }

  // ---- tail LN on xc ----
#pragma unroll
  for (int g = 0; g < 4; ++g) {
    float s = xc[g][0] + xc[g][1] + xc[g][2] + xc[g][3];
    float sq = xc[g][0] * xc[g][0] + xc[g][1] * xc[g][1] +
               xc[g][2] * xc[g][2] + xc[g][3] * xc[g][3];
    s += __shfl_xor(s, 16); sq += __shfl_xor(sq, 16);
    s += __shfl_xor(s, 32); sq += __shfl_xor(sq, 32);
    if (lane < 16) { LNS(g, wave, lr, 0) = s; LNS(g, wave, lr, 1) = sq; }
  }
  __syncthreads();  // B4 (all HSP reads done before XSH overlays)
  {
    f4 gg4 = *(const f4*)(lntg + cfo * 16 + lg * 4);
    f4 b4 = *(const f4*)(lntb + cfo * 16 + lg * 4);
#pragma unroll
    for (int g = 0; g < 4; ++g) {
      float s = 0.f, sq = 0.f;
#pragma unroll
      for (int w = 0; w < 6; ++w) { s += LNS(g, w, lr, 0); sq += LNS(g, w, lr, 1); }
      float mean = s * (1.f / 96.f);
      float rs = rsqrtf(sq * (1.f / 96.f) - mean * mean + 1e-5f);
      h4 xn;
#pragma unroll
      for (int j = 0; j < 4; ++j)
        xn[j] = (_Float16)((xc[g][j] - mean) * rs * gg4[j] + b4[j]);
      *(h4*)XSH(g, cfo * 16 + lr, lg * 4) = xn;
    }
  }
  __syncthreads();  // B5
  if constexpr (HEAD) {
    if (wave == 0) {
      h4 wt[6];
#pragma unroll
      for (int stp = 0; stp < 3; ++stp)
        ldpair(Wtail, stp, lane, wt[2 * stp], wt[2 * stp + 1]);
      f4 bb = *(const f4*)(btail + lg * 4);
#pragma unroll
      for (int g = 0; g < 4; ++g) {
        f4 a = zero4;
#pragma unroll
        for (int st = 0; st < 6; ++st) {
          h4 xf = *(const h4*)XSH(g, st * 16 + lr, lg * 4);
          a = MFMA16(wt[st], xf, a, 0, 0, 0);
        }
        f4 o;
#pragma unroll
        for (int j = 0; j < 4; ++j) o[j] = a[j] + bb[j];
        *(f4*)(out + (size_t)tok[g] * 16 + lg * 4) = o;
      }
    }
  } else {
    h4 xf[4][6];
#pragma unroll
    for (int g = 0; g < 4; ++g)
#pragma unroll
      for (int st = 0; st < 6; ++st)
        xf[g][st] = *(const h4*)XSH(g, st * 16 + lr, lg * 4);
    // tail frags: nf = wave*3 + f; Q:0-5 K:6-11 V:12-17
#pragma unroll
    for (int f = 0; f < 3; ++f) {
      int nf = wave * 3 + f;
      h4 wt[6];
#pragma unroll
      for (int stp = 0; stp < 3; ++stp)
        ldpair(Wtail, nf * 3 + stp, lane, wt[2 * stp], wt[2 * stp + 1]);
#pragma unroll
      for (int g = 0; g < 4; ++g) {
        int t2 = (row0b >> 5) + (g >> 1);
        f4 a = zero4;
#pragma unroll
        for (int st = 0; st < 6; ++st) a = MFMA16(wt[st], xf[g][st], a, 0, 0, 0);
        if (nf < 12) {  // Q or K paired tile: h4 at [lane][(g&1)*4]
          int h = nf < 6 ? nf : nf - 6;
          _Float16* dst = (nf < 6 ? qp_ : kp_) +
                          ((size_t)(bidx * NH_ + h) * 32 + t2) * 512 +
                          lane * 8 + (g & 1) * 4;
          h4 hv = {(_Float16)a[0], (_Float16)a[1], (_Float16)a[2], (_Float16)a[3]};
          *(h4*)dst = hv;
        } else {        // V paired tile: scalar scatter per r
          int hb = nf - 12;
          _Float16* vbase = vp_ + ((size_t)(bidx * NH_ + hb) * 32 + t2) * 512;
          int jb = (lr & 3) + (g & 1) * 4;
          int lgp = lr >> 2;
#pragma unroll
          for (int r = 0; r < 4; ++r)
            vbase[(lgp * 16 + lg * 4 + r) * 8 + jb] = (_Float16)a[r];
        }
      }
    }
  }
#undef XSH
#undef HSP
#undef LNS
#undef XP
}

// ---------- MFMA f16 flash attention: 32 q-rows/wave, paired tile loads ----
__global__ __launch_bounds__(256, 6) void attn_mfma_kernel(
    const _Float16* __restrict__ Qp, const _Float16* __restrict__ Kp,
    const _Float16* __restrict__ Vp, _Float16* __restrict__ obp) {
  int bh = blockIdx.x;
  int wave = threadIdx.x >> 6;
  int lane = threadIdx.x & 63;
  int qb = wave * 8 + blockIdx.y;    // 0..31
  int lr = lane & 15;
  int lg = lane >> 4;

  const _Float16* qB = Qp + (size_t)bh * 16384;
  const _Float16* kB = Kp + (size_t)bh * 16384;
  const _Float16* vB = Vp + (size_t)bh * 16384;

  h4 qf0, qf1;
  {
    h8 t = *(const h8*)(qB + (size_t)qb * 512 + lane * 8);
    qf0 = __builtin_shufflevector(t, t, 0, 1, 2, 3);
    qf1 = __builtin_shufflevector(t, t, 4, 5, 6, 7);
  }
  f4 O0 = {0.f, 0.f, 0.f, 0.f}, O1 = {0.f, 0.f, 0.f, 0.f};
  f4 S0 = {0.f, 0.f, 0.f, 0.f}, S1 = {0.f, 0.f, 0.f, 0.f};
  const f4 zero4 = {0.f, 0.f, 0.f, 0.f};
  const h4 ones = {(_Float16)1.f, (_Float16)1.f, (_Float16)1.f, (_Float16)1.f};

  h4 kc0, kc1, vc0, vc1, kn0, kn1, vn0, vn1;
  {
    h8 kt = *(const h8*)(kB + lane * 8);
    kc0 = __builtin_shufflevector(kt, kt, 0, 1, 2, 3);
    kc1 = __builtin_shufflevector(kt, kt, 4, 5, 6, 7);
    h8 vt8 = *(const h8*)(vB + lane * 8);
    vc0 = __builtin_shufflevector(vt8, vt8, 0, 1, 2, 3);
    vc1 = __builtin_shufflevector(vt8, vt8, 4, 5, 6, 7);
  }

  for (int tt = 0; tt < qb; ++tt) {
    {
      h8 kt = *(const h8*)(kB + (size_t)(tt + 1) * 512 + lane * 8);
      kn0 = __builtin_shufflevector(kt, kt, 0, 1, 2, 3);
      kn1 = __builtin_shufflevector(kt, kt, 4, 5, 6, 7);
      h8 vt8 = *(const h8*)(vB + (size_t)(tt + 1) * 512 + lane * 8);
      vn0 = __builtin_shufflevector(vt8, vt8, 0, 1, 2, 3);
      vn1 = __builtin_shufflevector(vt8, vt8, 4, 5, 6, 7);
    }
    f4 sa0 = MFMA16(kc0, qf0, zero4, 0, 0, 0);
    f4 sa1 = MFMA16(kc1, qf0, zero4, 0, 0, 0);
    f4 sb0 = MFMA16(kc0, qf1, zero4, 0, 0, 0);
    f4 sb1 = MFMA16(kc1, qf1, zero4, 0, 0, 0);
    float pa0[4], pa1[4], pb0[4], pb1[4];
#pragma unroll
    for (int r = 0; r < 4; ++r) {
      pa0[r] = __builtin_amdgcn_exp2f(sa0[r]);
      pa1[r] = __builtin_amdgcn_exp2f(sa1[r]);
      pb0[r] = __builtin_amdgcn_exp2f(sb0[r]);
      pb1[r] = __builtin_amdgcn_exp2f(sb1[r]);
    }
    h4 fa0 = pk4(pa0), fa1 = pk4(pa1), fb0 = pk4(pb0), fb1 = pk4(pb1);
    O0 = MFMA16(fa0, vc0, O0, 0, 0, 0);
    O0 = MFMA16(fa1, vc1, O0, 0, 0, 0);
    S0 = MFMA16(fa0, ones, S0, 0, 0, 0);
    S0 = MFMA16(fa1, ones, S0, 0, 0, 0);
    O1 = MFMA16(fb0, vc0, O1, 0, 0, 0);
    O1 = MFMA16(fb1, vc1, O1, 0, 0, 0);
    S1 = MFMA16(fb0, ones, S1, 0, 0, 0);
    S1 = MFMA16(fb1, ones, S1, 0, 0, 0);
    kc0 = kn0; kc1 = kn1; vc0 = vn0; vc1 = vn1;
  }

  {
    f4 sa0 = MFMA16(kc0, qf0, zero4, 0, 0, 0);
    float pa0[4];
#pragma unroll
    for (int r = 0; r < 4; ++r)
      pa0[r] = (lg * 4 + r <= lr) ? __builtin_amdgcn_exp2f(sa0[r]) : 0.f;
    h4 fa0 = pk4(pa0);
    O0 = MFMA16(fa0, vc0, O0, 0, 0, 0);
    S0 = MFMA16(fa0, ones, S0, 0, 0, 0);

    f4 sb0 = MFMA16(kc0, qf1, zero4, 0, 0, 0);
    f4 sb1 = MFMA16(kc1, qf1, zero4, 0, 0, 0);
    float pb0[4], pb1[4];
#pragma unroll
    for (int r = 0; r < 4; ++r) {
      pb0[r] = __builtin_amdgcn_exp2f(sb0[r]);
      pb1[r] = (lg * 4 + r <= lr) ? __builtin_amdgcn_exp2f(sb1[r]) : 0.f;
    }
    h4 fb0 = pk4(pb0), fb1 = pk4(pb1);
    O1 = MFMA16(fb0, vc0, O1, 0, 0, 0);
    O1 = MFMA16(fb1, vc1, O1, 0, 0, 0);
    S1 = MFMA16(fb0, ones, S1, 0, 0, 0);
    S1 = MFMA16(fb1, ones, S1, 0, 0, 0);
  }

  int b = bh / NH_, h = bh % NH_;
  int stp = h >> 1;
  int jb = (lr & 3) + (h & 1) * 4;
  int lgp = lr >> 2;
  size_t tb0 = (size_t)b * 64 + qb * 2;
#pragma unroll
  for (int r = 0; r < 4; ++r) {
    float li0 = __builtin_amdgcn_rcpf(S0[r]);
    float li1 = __builtin_amdgcn_rcpf(S1[r]);
    size_t pos = (size_t)(lgp * 16 + lg * 4 + r) * 8 + jb;
    obp[(tb0 * 3 + stp) * 512 + pos] = (_Float16)(O0[r] * li0);
    obp[((tb0 + 1) * 3 + stp) * 512 + pos] = (_Float16)(O1[r] * li1);
  }
}

extern "C" void kernel_launch(void* const* d_in, const int* in_sizes, int n_in,
                              void* d_out, int out_size, void* d_ws, size_t ws_size,
                              hipStream_t stream) {
  const float* goals   = (const float*)d_in[0];
  const float* obss    = (const float*)d_in[1];
  const float* w_go    = (const float*)d_in[2];
  const float* b_go    = (const float*)d_in[3];
  const float* pos_emb = (const float*)d_in[4];
  const float* wq      = (const float*)d_in[5];
  const float* wk      = (const float*)d_in[6];
  const float* wv      = (const float*)d_in[7];
  const float* w_proj  = (const float*)d_in[8];
  const float* b_proj  = (const float*)d_in[9];
  const float* ln1_g   = (const float*)d_in[10];
  const float* ln1_b   = (const float*)d_in[11];
  const float* ln2_g   = (const float*)d_in[12];
  const float* ln2_b   = (const float*)d_in[13];
  const float* w_ff1   = (const float*)d_in[14];
  const float* b_ff1   = (const float*)d_in[15];
  const float* w_ff2   = (const float*)d_in[16];
  const float* b_ff2   = (const float*)d_in[17];
  const float* lnf_g   = (const float*)d_in[18];
  const float* lnf_b   = (const float*)d_in[19];
  const float* w_act   = (const float*)d_in[20];
  const float* b_act   = (const float*)d_in[21];
  float* out = (float*)d_out;

  const int M = B_ * T_;  // 16384
  float* ws = (float*)d_ws;
  size_t off = 0;
  _Float16* P = (_Float16*)(ws + off); off += PACK_TOTAL / 2 + 64;
  float* x = ws + off; off += (size_t)M * 96;
  _Float16* obp = (_Float16*)(ws + off); off += (size_t)M * 48;
  _Float16* Qp = (_Float16*)(ws + off); off += (size_t)M * 48;
  _Float16* Kp = (_Float16*)(ws + off); off += (size_t)M * 48;
  _Float16* Vp = (_Float16*)(ws + off); off += (size_t)M * 48;

  pack_all_kernel<<<(PACK_TOTAL + 255) / 256, 256, 0, stream>>>(
      w_go, wq, wk, wv, w_proj, w_ff1, w_ff2, w_act, P);

  // embed + qkv(layer 0)
  stage_kernel<true, false><<<M / 64, 384, 0, stream>>>(
      goals, obss, pos_emb, b_go, nullptr, P + OFF_GO, nullptr, x,
      nullptr, nullptr, nullptr, nullptr, nullptr, nullptr,
      ln1_g, ln1_b, P + OFF_QKV, nullptr, Qp, Kp, Vp, nullptr);

  for (int l = 0; l < L_; ++l) {
    attn_mfma_kernel<<<dim3(B_ * NH_, 8), 256, 0, stream>>>(Qp, Kp, Vp, obp);
    if (l < L_ - 1) {
      stage_kernel<false, false><<<M / 64, 384, 0, stream>>>(
          nullptr, nullptr, nullptr, nullptr, obp,
          P + OFF_PROJ + (size_t)l * 9216, b_proj + l * 96, x,
          P + OFF_FF1 + (size_t)l * 36864, b_ff1 + l * 384,
          P + OFF_FF2 + (size_t)l * 36864, b_ff2 + l * 96,
          ln2_g + l * 96, ln2_b + l * 96,
          ln1_g + (l + 1) * 96, ln1_b + (l + 1) * 96,
          P + OFF_QKV + (size_t)(l + 1) * 27648, nullptr, Qp, Kp, Vp, nullptr);
    } else {
      stage_kernel<false, true><<<M / 64, 384, 0, stream>>>(
          nullptr, nullptr, nullptr, nullptr, obp,
          P + OFF_PROJ + (size_t)l * 9216, b_proj + l * 96, x,
          P + OFF_FF1 + (size_t)l * 36864, b_ff1 + l * 384,
          P + OFF_FF2 + (size_t)l * 36864, b_ff2 + l * 96,
          ln2_g + l * 96, ln2_b + l * 96,
          lnf_g, lnf_b, P + OFF_ACT, b_act, nullptr, nullptr, nullptr, out);
    }
  }
}

// Round 20
// 210.340 us; speedup vs baseline: 1.4530x; 1.0028x over previous
//
#include <hip/hip_runtime.h>
#include <math.h>

#define B_ 16
#define T_ 1024
#define D_ 96
#define L_ 6
#define NH_ 6
#define HS_ 16
#define FF_ 384

typedef _Float16 h4 __attribute__((ext_vector_type(4)));
typedef _Float16 h8 __attribute__((ext_vector_type(8)));
typedef __fp16 g2 __attribute__((ext_vector_type(2)));
typedef __fp16 g4 __attribute__((ext_vector_type(4)));
typedef float f4 __attribute__((ext_vector_type(4)));

#define MFMA16 __builtin_amdgcn_mfma_f32_16x16x16f16

// packed f16 weights, layout [frag][stp][lane 0..63][8 halves]
#define OFF_GO   0
#define OFF_QKV  9216
#define OFF_PROJ 175104
#define OFF_FF1  230400
#define OFF_FF2  451584
#define OFF_ACT  672768
#define PACK_TOTAL 674304

// Q weights pre-scaled by 1/sqrt(16) * log2(e) so attn uses exp2 directly.
#define QSCALE 0.3606737602222409f

static __device__ __forceinline__ h4 pk4(const float* p) {
  g2 lo = __builtin_amdgcn_cvt_pkrtz(p[0], p[1]);
  g2 hi = __builtin_amdgcn_cvt_pkrtz(p[2], p[3]);
  g4 r4 = __builtin_shufflevector(lo, hi, 0, 1, 2, 3);
  return __builtin_bit_cast(h4, r4);
}

static __device__ __forceinline__ void ldpair(const _Float16* base, int blk,
                                              int lane, h4& a, h4& b) {
  h8 t = *(const h8*)(base + (size_t)blk * 512 + lane * 8);
  a = __builtin_shufflevector(t, t, 0, 1, 2, 3);
  b = __builtin_shufflevector(t, t, 4, 5, 6, 7);
}

// ---------- pack all weights into paired-fragment layout ----------
__global__ __launch_bounds__(256) void pack_all_kernel(
    const float* __restrict__ w_go, const float* __restrict__ wq,
    const float* __restrict__ wk, const float* __restrict__ wv,
    const float* __restrict__ w_proj, const float* __restrict__ w_ff1,
    const float* __restrict__ w_ff2, const float* __restrict__ w_act,
    _Float16* __restrict__ P) {
  int i = blockIdx.x * 256 + threadIdx.x;
  if (i >= PACK_TOTAL) return;
  float v;
  if (i < OFF_QKV) {                       // GO: 6 frags, 3 stp
    int o = i, nf = o / 1536, r = o % 1536, stp = r / 512, q = r & 511;
    int lane = q >> 3, h8i = q & 7, lr = lane & 15, lg = lane >> 4;
    int st = stp * 2 + (h8i >> 2), j = h8i & 3;
    int n = nf * 16 + lr, k = st * 16 + lg * 4 + j;
    v = w_go[k * 96 + n];
  } else if (i < OFF_PROJ) {               // QKV: per layer 18 frags, 3 stp
    int o = i - OFF_QKV, l = o / 27648, r0 = o % 27648;
    int nf = r0 / 1536, r = r0 % 1536, stp = r / 512, q = r & 511;
    int lane = q >> 3, h8i = q & 7, lr = lane & 15, lg = lane >> 4;
    int st = stp * 2 + (h8i >> 2), j = h8i & 3;
    int c = nf * 16 + lr, k = st * 16 + lg * 4 + j;
    int which = c / 96, hc = c % 96, h = hc >> 4, jx = hc & 15;
    const float* s = (which == 0) ? wq : (which == 1 ? wk : wv);
    v = s[((l * NH_ + h) * 96 + k) * 16 + jx];
    if (which == 0) v *= QSCALE;
  } else if (i < OFF_FF1) {                // PROJ: per layer 6 frags, 3 stp
    int o = i - OFF_PROJ, l = o / 9216, r0 = o % 9216;
    int nf = r0 / 1536, r = r0 % 1536, stp = r / 512, q = r & 511;
    int lane = q >> 3, h8i = q & 7, lr = lane & 15, lg = lane >> 4;
    int st = stp * 2 + (h8i >> 2), j = h8i & 3;
    int n = nf * 16 + lr, k = st * 16 + lg * 4 + j;
    v = w_proj[l * 9216 + k * 96 + n];
  } else if (i < OFF_FF2) {                // FF1: per layer 24 frags, 3 stp
    int o = i - OFF_FF1, l = o / 36864, r0 = o % 36864;
    int nf = r0 / 1536, r = r0 % 1536, stp = r / 512, q = r & 511;
    int lane = q >> 3, h8i = q & 7, lr = lane & 15, lg = lane >> 4;
    int st = stp * 2 + (h8i >> 2), j = h8i & 3;
    int n = nf * 16 + lr, k = st * 16 + lg * 4 + j;
    v = w_ff1[l * 36864 + k * 384 + n];
  } else if (i < OFF_ACT) {                // FF2: per layer 6 frags, 12 stp
    int o = i - OFF_FF2, l = o / 36864, r0 = o % 36864;
    int nf = r0 / 6144, r = r0 % 6144, stp = r / 512, q = r & 511;
    int lane = q >> 3, h8i = q & 7, lr = lane & 15, lg = lane >> 4;
    int st = stp * 2 + (h8i >> 2), j = h8i & 3;
    int n = nf * 16 + lr, k = st * 16 + lg * 4 + j;
    v = w_ff2[l * 36864 + k * 96 + n];
  } else {                                 // ACT: 1 frag, 3 stp
    int o = i - OFF_ACT, stp = o / 512, q = o & 511;
    int lane = q >> 3, h8i = q & 7, lr = lane & 15, lg = lane >> 4;
    int st = stp * 2 + (h8i >> 2), j = h8i & 3;
    int k = st * 16 + lg * 4 + j;
    v = w_act[k * 16 + lr];
  }
  P[i] = (_Float16)v;
}

// ---------- fused stage kernel: 6 waves x 4 token-groups (64 tokens) ------
// Weight loads for each phase are ISSUED before the preceding barrier
// (hipcc drains vmcnt at barriers -> latency hides under LN/barrier work).
template <bool EMBED, bool HEAD>
__global__ __launch_bounds__(384, 1) void stage_kernel(
    const float* __restrict__ goals, const float* __restrict__ obss,
    const float* __restrict__ pos, const float* __restrict__ b_go,
    const _Float16* __restrict__ obp, const _Float16* __restrict__ Wp,
    const float* __restrict__ bp, float* __restrict__ x,
    const _Float16* __restrict__ W1, const float* __restrict__ b1,
    const _Float16* __restrict__ W2, const float* __restrict__ b2,
    const float* __restrict__ ln2g, const float* __restrict__ ln2b,
    const float* __restrict__ lntg, const float* __restrict__ lntb,
    const _Float16* __restrict__ Wtail, const float* __restrict__ btail,
    _Float16* __restrict__ qp_, _Float16* __restrict__ kp_,
    _Float16* __restrict__ vp_, float* __restrict__ out) {
  __shared__ float smemf[16128];  // 64512 B
#define XSH(g, row, c) ((_Float16*)smemf + (size_t)(g) * 1920 + (row) * 20 + (c))
#define HSP(g, fp) ((_Float16*)smemf + ((size_t)(g) * 12 + (fp)) * 512)
#define LNS(g, w, r, i) smemf[15360 + (((g) * 6 + (w)) * 16 + (r)) * 2 + (i)]
#define XP(g) (x + ((size_t)(blockIdx.x * 4 + (g)) * 6 + cfo) * 256 + lane * 4)
  const int tid = threadIdx.x;
  const int wave = tid >> 6, lane = tid & 63;
  const int lr = lane & 15, lg = lane >> 4;
  const int row0 = blockIdx.x * 64;
  const int bidx = row0 >> 10;
  const int row0b = row0 & 1023;
  const int cfo = wave;  // owned col-frag 0..5
  const f4 zero4 = {0.f, 0.f, 0.f, 0.f};
  int tok[4], tt[4];
#pragma unroll
  for (int g = 0; g < 4; ++g) { tok[g] = row0 + g * 16 + lr; tt[g] = tok[g] & 1023; }

  f4 xc[4], x1[4];

  if constexpr (EMBED) {
    h4 ef[4][6];
#pragma unroll
    for (int st = 0; st < 2; ++st) {
      f4 s4 = *(const f4*)(goals + bidx * 32 + st * 16 + lg * 4);
      h4 e = (h4){(_Float16)s4[0], (_Float16)s4[1], (_Float16)s4[2], (_Float16)s4[3]};
#pragma unroll
      for (int g = 0; g < 4; ++g) ef[g][st] = e;
    }
#pragma unroll
    for (int g = 0; g < 4; ++g)
#pragma unroll
      for (int st = 2; st < 6; ++st) {
        f4 s4 = *(const f4*)(obss + (size_t)(bidx * 1024 + tt[g]) * 64 +
                             (st - 2) * 16 + lg * 4);
        ef[g][st] = (h4){(_Float16)s4[0], (_Float16)s4[1], (_Float16)s4[2], (_Float16)s4[3]};
      }
    h4 wf[6];
#pragma unroll
    for (int stp = 0; stp < 3; ++stp)
      ldpair(Wp, cfo * 3 + stp, lane, wf[2 * stp], wf[2 * stp + 1]);
    f4 bb = *(const f4*)(b_go + cfo * 16 + lg * 4);
#pragma unroll
    for (int g = 0; g < 4; ++g) {
      f4 a = zero4;
#pragma unroll
      for (int st = 0; st < 6; ++st) a = MFMA16(wf[st], ef[g][st], a, 0, 0, 0);
      f4 pp = *(const f4*)(pos + (size_t)tt[g] * 96 + cfo * 16 + lg * 4);
#pragma unroll
      for (int j = 0; j < 4; ++j) xc[g][j] = a[j] + bb[j] + pp[j];
      *(f4*)XP(g) = xc[g];
    }
  } else {
    // ---- proj + resid: obf via paired h8 loads ----
    h4 obf[4][6];
#pragma unroll
    for (int g = 0; g < 4; ++g)
#pragma unroll
      for (int stp = 0; stp < 3; ++stp)
        ldpair(obp, (blockIdx.x * 4 + g) * 3 + stp, lane,
               obf[g][2 * stp], obf[g][2 * stp + 1]);
    h4 wf[6];
#pragma unroll
    for (int stp = 0; stp < 3; ++stp)
      ldpair(Wp, cfo * 3 + stp, lane, wf[2 * stp], wf[2 * stp + 1]);
    f4 bb = *(const f4*)(bp + cfo * 16 + lg * 4);
#pragma unroll
    for (int g = 0; g < 4; ++g) {
      f4 a = zero4;
#pragma unroll
      for (int st = 0; st < 6; ++st) a = MFMA16(wf[st], obf[g][st], a, 0, 0, 0);
      f4 xr = *(const f4*)XP(g);
#pragma unroll
      for (int j = 0; j < 4; ++j) x1[g][j] = a[j] + bb[j] + xr[j];
    }

    // ---- PREFETCH ff1 + ff2 weights (complete by B1/B2; used after B2b) ----
    h4 w1A[4][6];
#pragma unroll
    for (int f = 0; f < 4; ++f)
#pragma unroll
      for (int stp = 0; stp < 3; ++stp)
        ldpair(W1, (wave * 4 + f) * 3 + stp, lane, w1A[f][2 * stp], w1A[f][2 * stp + 1]);
    f4 b1r[4];
#pragma unroll
    for (int f = 0; f < 4; ++f)
      b1r[f] = *(const f4*)(b1 + (wave * 4 + f) * 16 + lg * 4);
    h4 w2f[24];
#pragma unroll
    for (int stp = 0; stp < 12; ++stp)
      ldpair(W2, cfo * 12 + stp, lane, w2f[2 * stp], w2f[2 * stp + 1]);

    // ---- LN2 partials ----
#pragma unroll
    for (int g = 0; g < 4; ++g) {
      float s = x1[g][0] + x1[g][1] + x1[g][2] + x1[g][3];
      float sq = x1[g][0] * x1[g][0] + x1[g][1] * x1[g][1] +
                 x1[g][2] * x1[g][2] + x1[g][3] * x1[g][3];
      s += __shfl_xor(s, 16); sq += __shfl_xor(sq, 16);
      s += __shfl_xor(s, 32); sq += __shfl_xor(sq, 32);
      if (lane < 16) { LNS(g, wave, lr, 0) = s; LNS(g, wave, lr, 1) = sq; }
    }
    __syncthreads();  // B1
    {
      f4 gg4 = *(const f4*)(ln2g + cfo * 16 + lg * 4);
      f4 b4 = *(const f4*)(ln2b + cfo * 16 + lg * 4);
#pragma unroll
      for (int g = 0; g < 4; ++g) {
        float s = 0.f, sq = 0.f;
#pragma unroll
        for (int w = 0; w < 6; ++w) { s += LNS(g, w, lr, 0); sq += LNS(g, w, lr, 1); }
        float mean = s * (1.f / 96.f);
        float rs = rsqrtf(sq * (1.f / 96.f) - mean * mean + 1e-5f);
        h4 xn;
#pragma unroll
        for (int j = 0; j < 4; ++j)
          xn[j] = (_Float16)((x1[g][j] - mean) * rs * gg4[j] + b4[j]);
        *(h4*)XSH(g, cfo * 16 + lr, lg * 4) = xn;
      }
    }
    __syncthreads();  // B2
    h4 xnf[4][6];
#pragma unroll
    for (int g = 0; g < 4; ++g)
#pragma unroll
      for (int st = 0; st < 6; ++st)
        xnf[g][st] = *(const h4*)XSH(g, st * 16 + lr, lg * 4);
    __syncthreads();  // B2b (xn fully read before HSP overlays it)

    // ---- ff1 + relu -> HSP pairs (weights preloaded) ----
#pragma unroll
    for (int p = 0; p < 2; ++p) {
      int f0 = p * 2;
#pragma unroll
      for (int g = 0; g < 4; ++g) {
        f4 hA = zero4, hB = zero4;
#pragma unroll
        for (int st = 0; st < 6; ++st) {
          hA = MFMA16(w1A[f0][st], xnf[g][st], hA, 0, 0, 0);
          hB = MFMA16(w1A[f0 + 1][st], xnf[g][st], hB, 0, 0, 0);
        }
        h4 lo, hi;
#pragma unroll
        for (int j = 0; j < 4; ++j) {
          lo[j] = (_Float16)fmaxf(hA[j] + b1r[f0][j], 0.f);
          hi[j] = (_Float16)fmaxf(hB[j] + b1r[f0 + 1][j], 0.f);
        }
        h8 comb = __builtin_shufflevector(lo, hi, 0, 1, 2, 3, 4, 5, 6, 7);
        *(h8*)(HSP(g, wave * 2 + p) + lane * 8) = comb;
      }
    }
    __syncthreads();  // B3 (all hf written)
    {
      f4 b4 = *(const f4*)(b2 + cfo * 16 + lg * 4);
#pragma unroll
      for (int g = 0; g < 4; ++g) {
        f4 y = zero4;
#pragma unroll
        for (int fp = 0; fp < 12; ++fp) {
          h8 t = *(const h8*)(HSP(g, fp) + lane * 8);
          h4 lo = __builtin_shufflevector(t, t, 0, 1, 2, 3);
          h4 hi = __builtin_shufflevector(t, t, 4, 5, 6, 7);
          y = MFMA16(w2f[2 * fp], lo, y, 0, 0, 0);
          y = MFMA16(w2f[2 * fp + 1], hi, y, 0, 0, 0);
        }
#pragma unroll
        for (int j = 0; j < 4; ++j) xc[g][j] = x1[g][j] + y[j] + b4[j];
        if constexpr (!HEAD)
          *(f4*)XP(g) = xc[g];
      }
    }
  }

  // ---- PREFETCH tail weights (complete by B4; used after B5) ----
  h4 wt[3][6];
  if constexpr (HEAD) {
    if (wave == 0) {
#pragma unroll
      for (int stp = 0; stp < 3; ++stp)
        ldpair(Wtail, stp, lane, wt[0][2 * stp], wt[0][2 * stp + 1]);
    }
  } else {
#pragma unroll
    for (int f = 0; f < 3; ++f)
#pragma unroll
      for (int stp = 0; stp < 3; ++stp)
        ldpair(Wtail, (wave * 3 + f) * 3 + stp, lane, wt[f][2 * stp], wt[f][2 * stp + 1]);
  }

  // ---- tail LN on xc ----
#pragma unroll
  for (int g = 0; g < 4; ++g) {
    float s = xc[g][0] + xc[g][1] + xc[g][2] + xc[g][3];
    float sq = xc[g][0] * xc[g][0] + xc[g][1] * xc[g][1] +
               xc[g][2] * xc[g][2] + xc[g][3] * xc[g][3];
    s += __shfl_xor(s, 16); sq += __shfl_xor(sq, 16);
    s += __shfl_xor(s, 32); sq += __shfl_xor(sq, 32);
    if (lane < 16) { LNS(g, wave, lr, 0) = s; LNS(g, wave, lr, 1) = sq; }
  }
  __syncthreads();  // B4 (all HSP reads done before XSH overlays)
  {
    f4 gg4 = *(const f4*)(lntg + cfo * 16 + lg * 4);
    f4 b4 = *(const f4*)(lntb + cfo * 16 + lg * 4);
#pragma unroll
    for (int g = 0; g < 4; ++g) {
      float s = 0.f, sq = 0.f;
#pragma unroll
      for (int w = 0; w < 6; ++w) { s += LNS(g, w, lr, 0); sq += LNS(g, w, lr, 1); }
      float mean = s * (1.f / 96.f);
      float rs = rsqrtf(sq * (1.f / 96.f) - mean * mean + 1e-5f);
      h4 xn;
#pragma unroll
      for (int j = 0; j < 4; ++j)
        xn[j] = (_Float16)((xc[g][j] - mean) * rs * gg4[j] + b4[j]);
      *(h4*)XSH(g, cfo * 16 + lr, lg * 4) = xn;
    }
  }
  __syncthreads();  // B5
  if constexpr (HEAD) {
    if (wave == 0) {
      f4 bb = *(const f4*)(btail + lg * 4);
#pragma unroll
      for (int g = 0; g < 4; ++g) {
        f4 a = zero4;
#pragma unroll
        for (int st = 0; st < 6; ++st) {
          h4 xf = *(const h4*)XSH(g, st * 16 + lr, lg * 4);
          a = MFMA16(wt[0][st], xf, a, 0, 0, 0);
        }
        f4 o;
#pragma unroll
        for (int j = 0; j < 4; ++j) o[j] = a[j] + bb[j];
        *(f4*)(out + (size_t)tok[g] * 16 + lg * 4) = o;
      }
    }
  } else {
    h4 xf[4][6];
#pragma unroll
    for (int g = 0; g < 4; ++g)
#pragma unroll
      for (int st = 0; st < 6; ++st)
        xf[g][st] = *(const h4*)XSH(g, st * 16 + lr, lg * 4);
    // tail frags: nf = wave*3 + f; Q:0-5 K:6-11 V:12-17
#pragma unroll
    for (int f = 0; f < 3; ++f) {
      int nf = wave * 3 + f;
#pragma unroll
      for (int g = 0; g < 4; ++g) {
        int t2 = (row0b >> 5) + (g >> 1);
        f4 a = zero4;
#pragma unroll
        for (int st = 0; st < 6; ++st) a = MFMA16(wt[f][st], xf[g][st], a, 0, 0, 0);
        if (nf < 12) {  // Q or K paired tile: h4 at [lane][(g&1)*4]
          int h = nf < 6 ? nf : nf - 6;
          _Float16* dst = (nf < 6 ? qp_ : kp_) +
                          ((size_t)(bidx * NH_ + h) * 32 + t2) * 512 +
                          lane * 8 + (g & 1) * 4;
          h4 hv = {(_Float16)a[0], (_Float16)a[1], (_Float16)a[2], (_Float16)a[3]};
          *(h4*)dst = hv;
        } else {        // V paired tile: scalar scatter per r
          int hb = nf - 12;
          _Float16* vbase = vp_ + ((size_t)(bidx * NH_ + hb) * 32 + t2) * 512;
          int jb = (lr & 3) + (g & 1) * 4;
          int lgp = lr >> 2;
#pragma unroll
          for (int r = 0; r < 4; ++r)
            vbase[(lgp * 16 + lg * 4 + r) * 8 + jb] = (_Float16)a[r];
        }
      }
    }
  }
#undef XSH
#undef HSP
#undef LNS
#undef XP
}

// ---------- MFMA f16 flash attention: 32 q-rows/wave, paired tile loads ----
__global__ __launch_bounds__(256, 6) void attn_mfma_kernel(
    const _Float16* __restrict__ Qp, const _Float16* __restrict__ Kp,
    const _Float16* __restrict__ Vp, _Float16* __restrict__ obp) {
  int bh = blockIdx.x;
  int wave = threadIdx.x >> 6;
  int lane = threadIdx.x & 63;
  int qb = wave * 8 + blockIdx.y;    // 0..31
  int lr = lane & 15;
  int lg = lane >> 4;

  const _Float16* qB = Qp + (size_t)bh * 16384;
  const _Float16* kB = Kp + (size_t)bh * 16384;
  const _Float16* vB = Vp + (size_t)bh * 16384;

  h4 qf0, qf1;
  {
    h8 t = *(const h8*)(qB + (size_t)qb * 512 + lane * 8);
    qf0 = __builtin_shufflevector(t, t, 0, 1, 2, 3);
    qf1 = __builtin_shufflevector(t, t, 4, 5, 6, 7);
  }
  f4 O0 = {0.f, 0.f, 0.f, 0.f}, O1 = {0.f, 0.f, 0.f, 0.f};
  f4 S0 = {0.f, 0.f, 0.f, 0.f}, S1 = {0.f, 0.f, 0.f, 0.f};
  const f4 zero4 = {0.f, 0.f, 0.f, 0.f};
  const h4 ones = {(_Float16)1.f, (_Float16)1.f, (_Float16)1.f, (_Float16)1.f};

  h4 kc0, kc1, vc0, vc1, kn0, kn1, vn0, vn1;
  {
    h8 kt = *(const h8*)(kB + lane * 8);
    kc0 = __builtin_shufflevector(kt, kt, 0, 1, 2, 3);
    kc1 = __builtin_shufflevector(kt, kt, 4, 5, 6, 7);
    h8 vt8 = *(const h8*)(vB + lane * 8);
    vc0 = __builtin_shufflevector(vt8, vt8, 0, 1, 2, 3);
    vc1 = __builtin_shufflevector(vt8, vt8, 4, 5, 6, 7);
  }

  for (int tt = 0; tt < qb; ++tt) {
    {
      h8 kt = *(const h8*)(kB + (size_t)(tt + 1) * 512 + lane * 8);
      kn0 = __builtin_shufflevector(kt, kt, 0, 1, 2, 3);
      kn1 = __builtin_shufflevector(kt, kt, 4, 5, 6, 7);
      h8 vt8 = *(const h8*)(vB + (size_t)(tt + 1) * 512 + lane * 8);
      vn0 = __builtin_shufflevector(vt8, vt8, 0, 1, 2, 3);
      vn1 = __builtin_shufflevector(vt8, vt8, 4, 5, 6, 7);
    }
    f4 sa0 = MFMA16(kc0, qf0, zero4, 0, 0, 0);
    f4 sa1 = MFMA16(kc1, qf0, zero4, 0, 0, 0);
    f4 sb0 = MFMA16(kc0, qf1, zero4, 0, 0, 0);
    f4 sb1 = MFMA16(kc1, qf1, zero4, 0, 0, 0);
    float pa0[4], pa1[4], pb0[4], pb1[4];
#pragma unroll
    for (int r = 0; r < 4; ++r) {
      pa0[r] = __builtin_amdgcn_exp2f(sa0[r]);
      pa1[r] = __builtin_amdgcn_exp2f(sa1[r]);
      pb0[r] = __builtin_amdgcn_exp2f(sb0[r]);
      pb1[r] = __builtin_amdgcn_exp2f(sb1[r]);
    }
    h4 fa0 = pk4(pa0), fa1 = pk4(pa1), fb0 = pk4(pb0), fb1 = pk4(pb1);
    O0 = MFMA16(fa0, vc0, O0, 0, 0, 0);
    O0 = MFMA16(fa1, vc1, O0, 0, 0, 0);
    S0 = MFMA16(fa0, ones, S0, 0, 0, 0);
    S0 = MFMA16(fa1, ones, S0, 0, 0, 0);
    O1 = MFMA16(fb0, vc0, O1, 0, 0, 0);
    O1 = MFMA16(fb1, vc1, O1, 0, 0, 0);
    S1 = MFMA16(fb0, ones, S1, 0, 0, 0);
    S1 = MFMA16(fb1, ones, S1, 0, 0, 0);
    kc0 = kn0; kc1 = kn1; vc0 = vn0; vc1 = vn1;
  }

  {
    f4 sa0 = MFMA16(kc0, qf0, zero4, 0, 0, 0);
    float pa0[4];
#pragma unroll
    for (int r = 0; r < 4; ++r)
      pa0[r] = (lg * 4 + r <= lr) ? __builtin_amdgcn_exp2f(sa0[r]) : 0.f;
    h4 fa0 = pk4(pa0);
    O0 = MFMA16(fa0, vc0, O0, 0, 0, 0);
    S0 = MFMA16(fa0, ones, S0, 0, 0, 0);

    f4 sb0 = MFMA16(kc0, qf1, zero4, 0, 0, 0);
    f4 sb1 = MFMA16(kc1, qf1, zero4, 0, 0, 0);
    float pb0[4], pb1[4];
#pragma unroll
    for (int r = 0; r < 4; ++r) {
      pb0[r] = __builtin_amdgcn_exp2f(sb0[r]);
      pb1[r] = (lg * 4 + r <= lr) ? __builtin_amdgcn_exp2f(sb1[r]) : 0.f;
    }
    h4 fb0 = pk4(pb0), fb1 = pk4(pb1);
    O1 = MFMA16(fb0, vc0, O1, 0, 0, 0);
    O1 = MFMA16(fb1, vc1, O1, 0, 0, 0);
    S1 = MFMA16(fb0, ones, S1, 0, 0, 0);
    S1 = MFMA16(fb1, ones, S1, 0, 0, 0);
  }

  int b = bh / NH_, h = bh % NH_;
  int stp = h >> 1;
  int jb = (lr & 3) + (h & 1) * 4;
  int lgp = lr >> 2;
  size_t tb0 = (size_t)b * 64 + qb * 2;
#pragma unroll
  for (int r = 0; r < 4; ++r) {
    float li0 = __builtin_amdgcn_rcpf(S0[r]);
    float li1 = __builtin_amdgcn_rcpf(S1[r]);
    size_t pos = (size_t)(lgp * 16 + lg * 4 + r) * 8 + jb;
    obp[(tb0 * 3 + stp) * 512 + pos] = (_Float16)(O0[r] * li0);
    obp[((tb0 + 1) * 3 + stp) * 512 + pos] = (_Float16)(O1[r] * li1);
  }
}

extern "C" void kernel_launch(void* const* d_in, const int* in_sizes, int n_in,
                              void* d_out, int out_size, void* d_ws, size_t ws_size,
                              hipStream_t stream) {
  const float* goals   = (const float*)d_in[0];
  const float* obss    = (const float*)d_in[1];
  const float* w_go    = (const float*)d_in[2];
  const float* b_go    = (const float*)d_in[3];
  const float* pos_emb = (const float*)d_in[4];
  const float* wq      = (const float*)d_in[5];
  const float* wk      = (const float*)d_in[6];
  const float* wv      = (const float*)d_in[7];
  const float* w_proj  = (const float*)d_in[8];
  const float* b_proj  = (const float*)d_in[9];
  const float* ln1_g   = (const float*)d_in[10];
  const float* ln1_b   = (const float*)d_in[11];
  const float* ln2_g   = (const float*)d_in[12];
  const float* ln2_b   = (const float*)d_in[13];
  const float* w_ff1   = (const float*)d_in[14];
  const float* b_ff1   = (const float*)d_in[15];
  const float* w_ff2   = (const float*)d_in[16];
  const float* b_ff2   = (const float*)d_in[17];
  const float* lnf_g   = (const float*)d_in[18];
  const float* lnf_b   = (const float*)d_in[19];
  const float* w_act   = (const float*)d_in[20];
  const float* b_act   = (const float*)d_in[21];
  float* out = (float*)d_out;

  const int M = B_ * T_;  // 16384
  float* ws = (float*)d_ws;
  size_t off = 0;
  _Float16* P = (_Float16*)(ws + off); off += PACK_TOTAL / 2 + 64;
  float* x = ws + off; off += (size_t)M * 96;
  _Float16* obp = (_Float16*)(ws + off); off += (size_t)M * 48;
  _Float16* Qp = (_Float16*)(ws + off); off += (size_t)M * 48;
  _Float16* Kp = (_Float16*)(ws + off); off += (size_t)M * 48;
  _Float16* Vp = (_Float16*)(ws + off); off += (size_t)M * 48;

  pack_all_kernel<<<(PACK_TOTAL + 255) / 256, 256, 0, stream>>>(
      w_go, wq, wk, wv, w_proj, w_ff1, w_ff2, w_act, P);

  // embed + qkv(layer 0)
  stage_kernel<true, false><<<M / 64, 384, 0, stream>>>(
      goals, obss, pos_emb, b_go, nullptr, P + OFF_GO, nullptr, x,
      nullptr, nullptr, nullptr, nullptr, nullptr, nullptr,
      ln1_g, ln1_b, P + OFF_QKV, nullptr, Qp, Kp, Vp, nullptr);

  for (int l = 0; l < L_; ++l) {
    attn_mfma_kernel<<<dim3(B_ * NH_, 8), 256, 0, stream>>>(Qp, Kp, Vp, obp);
    if (l < L_ - 1) {
      stage_kernel<false, false><<<M / 64, 384, 0, stream>>>(
          nullptr, nullptr, nullptr, nullptr, obp,
          P + OFF_PROJ + (size_t)l * 9216, b_proj + l * 96, x,
          P + OFF_FF1 + (size_t)l * 36864, b_ff1 + l * 384,
          P + OFF_FF2 + (size_t)l * 36864, b_ff2 + l * 96,
          ln2_g + l * 96, ln2_b + l * 96,
          ln1_g + (l + 1) * 96, ln1_b + (l + 1) * 96,
          P + OFF_QKV + (size_t)(l + 1) * 27648, nullptr, Qp, Kp, Vp, nullptr);
    } else {
      stage_kernel<false, true><<<M / 64, 384, 0, stream>>>(
          nullptr, nullptr, nullptr, nullptr, obp,
          P + OFF_PROJ + (size_t)l * 9216, b_proj + l * 96, x,
          P + OFF_FF1 + (size_t)l * 36864, b_ff1 + l * 384,
          P + OFF_FF2 + (size_t)l * 36864, b_ff2 + l * 96,
          ln2_g + l * 96, ln2_b + l * 96,
          lnf_g, lnf_b, P + OFF_ACT, b_act, nullptr, nullptr, nullptr, out);
    }
  }
}

// Round 21
// 186.089 us; speedup vs baseline: 1.6424x; 1.1303x over previous
//
#include <hip/hip_runtime.h>
#include <math.h>

#define B_ 16
#define T_ 1024
#define D_ 96
#define L_ 6
#define NH_ 6
#define HS_ 16
#define FF_ 384

typedef _Float16 h4 __attribute__((ext_vector_type(4)));
typedef _Float16 h8 __attribute__((ext_vector_type(8)));
typedef __fp16 g2 __attribute__((ext_vector_type(2)));
typedef __fp16 g4 __attribute__((ext_vector_type(4)));
typedef float f4 __attribute__((ext_vector_type(4)));

#define MFMA16 __builtin_amdgcn_mfma_f32_16x16x16f16

// packed f16 weights, layout [frag][stp][lane 0..63][8 halves]
#define OFF_GO   0
#define OFF_QKV  9216
#define OFF_PROJ 175104
#define OFF_FF1  230400
#define OFF_FF2  451584
#define OFF_ACT  672768
#define PACK_TOTAL 674304

// Q weights pre-scaled by 1/sqrt(16) * log2(e) so attn uses exp2 directly.
#define QSCALE 0.3606737602222409f

static __device__ __forceinline__ h4 pk4(const float* p) {
  g2 lo = __builtin_amdgcn_cvt_pkrtz(p[0], p[1]);
  g2 hi = __builtin_amdgcn_cvt_pkrtz(p[2], p[3]);
  g4 r4 = __builtin_shufflevector(lo, hi, 0, 1, 2, 3);
  return __builtin_bit_cast(h4, r4);
}

static __device__ __forceinline__ void ldpair(const _Float16* base, int blk,
                                              int lane, h4& a, h4& b) {
  h8 t = *(const h8*)(base + (size_t)blk * 512 + lane * 8);
  a = __builtin_shufflevector(t, t, 0, 1, 2, 3);
  b = __builtin_shufflevector(t, t, 4, 5, 6, 7);
}

static __device__ __forceinline__ void ldkv(const _Float16* kB_, const _Float16* vB_,
                                            int tile, int lane,
                                            h4& k0, h4& k1, h4& v0, h4& v1) {
  h8 kt = *(const h8*)(kB_ + (size_t)tile * 512 + lane * 8);
  k0 = __builtin_shufflevector(kt, kt, 0, 1, 2, 3);
  k1 = __builtin_shufflevector(kt, kt, 4, 5, 6, 7);
  h8 vt = *(const h8*)(vB_ + (size_t)tile * 512 + lane * 8);
  v0 = __builtin_shufflevector(vt, vt, 0, 1, 2, 3);
  v1 = __builtin_shufflevector(vt, vt, 4, 5, 6, 7);
}

// full tile step: 2 q-subtiles vs one K/V tile
static __device__ __forceinline__ void astep_full(
    const h4& kc0, const h4& kc1, const h4& vc0, const h4& vc1,
    const h4& qf0, const h4& qf1, const h4& ones,
    f4& O0, f4& O1, f4& S0, f4& S1) {
  const f4 zero4 = {0.f, 0.f, 0.f, 0.f};
  f4 sa0 = MFMA16(kc0, qf0, zero4, 0, 0, 0);
  f4 sa1 = MFMA16(kc1, qf0, zero4, 0, 0, 0);
  f4 sb0 = MFMA16(kc0, qf1, zero4, 0, 0, 0);
  f4 sb1 = MFMA16(kc1, qf1, zero4, 0, 0, 0);
  float pa0[4], pa1[4], pb0[4], pb1[4];
#pragma unroll
  for (int r = 0; r < 4; ++r) {
    pa0[r] = __builtin_amdgcn_exp2f(sa0[r]);
    pa1[r] = __builtin_amdgcn_exp2f(sa1[r]);
    pb0[r] = __builtin_amdgcn_exp2f(sb0[r]);
    pb1[r] = __builtin_amdgcn_exp2f(sb1[r]);
  }
  h4 fa0 = pk4(pa0), fa1 = pk4(pa1), fb0 = pk4(pb0), fb1 = pk4(pb1);
  O0 = MFMA16(fa0, vc0, O0, 0, 0, 0);
  O0 = MFMA16(fa1, vc1, O0, 0, 0, 0);
  S0 = MFMA16(fa0, ones, S0, 0, 0, 0);
  S0 = MFMA16(fa1, ones, S0, 0, 0, 0);
  O1 = MFMA16(fb0, vc0, O1, 0, 0, 0);
  O1 = MFMA16(fb1, vc1, O1, 0, 0, 0);
  S1 = MFMA16(fb0, ones, S1, 0, 0, 0);
  S1 = MFMA16(fb1, ones, S1, 0, 0, 0);
}

// diagonal tile step (causal): u0 sees half0 masked; u1 half0 full + half1 masked
static __device__ __forceinline__ void astep_diag(
    const h4& kc0, const h4& kc1, const h4& vc0, const h4& vc1,
    const h4& qf0, const h4& qf1, const h4& ones,
    f4& O0, f4& O1, f4& S0, f4& S1, int lr, int lg) {
  const f4 zero4 = {0.f, 0.f, 0.f, 0.f};
  f4 sa0 = MFMA16(kc0, qf0, zero4, 0, 0, 0);
  float pa0[4];
#pragma unroll
  for (int r = 0; r < 4; ++r)
    pa0[r] = (lg * 4 + r <= lr) ? __builtin_amdgcn_exp2f(sa0[r]) : 0.f;
  h4 fa0 = pk4(pa0);
  O0 = MFMA16(fa0, vc0, O0, 0, 0, 0);
  S0 = MFMA16(fa0, ones, S0, 0, 0, 0);
  f4 sb0 = MFMA16(kc0, qf1, zero4, 0, 0, 0);
  f4 sb1 = MFMA16(kc1, qf1, zero4, 0, 0, 0);
  float pb0[4], pb1[4];
#pragma unroll
  for (int r = 0; r < 4; ++r) {
    pb0[r] = __builtin_amdgcn_exp2f(sb0[r]);
    pb1[r] = (lg * 4 + r <= lr) ? __builtin_amdgcn_exp2f(sb1[r]) : 0.f;
  }
  h4 fb0 = pk4(pb0), fb1 = pk4(pb1);
  O1 = MFMA16(fb0, vc0, O1, 0, 0, 0);
  O1 = MFMA16(fb1, vc1, O1, 0, 0, 0);
  S1 = MFMA16(fb0, ones, S1, 0, 0, 0);
  S1 = MFMA16(fb1, ones, S1, 0, 0, 0);
}

// ---------- pack all weights into paired-fragment layout ----------
__global__ __launch_bounds__(256) void pack_all_kernel(
    const float* __restrict__ w_go, const float* __restrict__ wq,
    const float* __restrict__ wk, const float* __restrict__ wv,
    const float* __restrict__ w_proj, const float* __restrict__ w_ff1,
    const float* __restrict__ w_ff2, const float* __restrict__ w_act,
    _Float16* __restrict__ P) {
  int i = blockIdx.x * 256 + threadIdx.x;
  if (i >= PACK_TOTAL) return;
  float v;
  if (i < OFF_QKV) {                       // GO: 6 frags, 3 stp
    int o = i, nf = o / 1536, r = o % 1536, stp = r / 512, q = r & 511;
    int lane = q >> 3, h8i = q & 7, lr = lane & 15, lg = lane >> 4;
    int st = stp * 2 + (h8i >> 2), j = h8i & 3;
    int n = nf * 16 + lr, k = st * 16 + lg * 4 + j;
    v = w_go[k * 96 + n];
  } else if (i < OFF_PROJ) {               // QKV: per layer 18 frags, 3 stp
    int o = i - OFF_QKV, l = o / 27648, r0 = o % 27648;
    int nf = r0 / 1536, r = r0 % 1536, stp = r / 512, q = r & 511;
    int lane = q >> 3, h8i = q & 7, lr = lane & 15, lg = lane >> 4;
    int st = stp * 2 + (h8i >> 2), j = h8i & 3;
    int c = nf * 16 + lr, k = st * 16 + lg * 4 + j;
    int which = c / 96, hc = c % 96, h = hc >> 4, jx = hc & 15;
    const float* s = (which == 0) ? wq : (which == 1 ? wk : wv);
    v = s[((l * NH_ + h) * 96 + k) * 16 + jx];
    if (which == 0) v *= QSCALE;
  } else if (i < OFF_FF1) {                // PROJ: per layer 6 frags, 3 stp
    int o = i - OFF_PROJ, l = o / 9216, r0 = o % 9216;
    int nf = r0 / 1536, r = r0 % 1536, stp = r / 512, q = r & 511;
    int lane = q >> 3, h8i = q & 7, lr = lane & 15, lg = lane >> 4;
    int st = stp * 2 + (h8i >> 2), j = h8i & 3;
    int n = nf * 16 + lr, k = st * 16 + lg * 4 + j;
    v = w_proj[l * 9216 + k * 96 + n];
  } else if (i < OFF_FF2) {                // FF1: per layer 24 frags, 3 stp
    int o = i - OFF_FF1, l = o / 36864, r0 = o % 36864;
    int nf = r0 / 1536, r = r0 % 1536, stp = r / 512, q = r & 511;
    int lane = q >> 3, h8i = q & 7, lr = lane & 15, lg = lane >> 4;
    int st = stp * 2 + (h8i >> 2), j = h8i & 3;
    int n = nf * 16 + lr, k = st * 16 + lg * 4 + j;
    v = w_ff1[l * 36864 + k * 384 + n];
  } else if (i < OFF_ACT) {                // FF2: per layer 6 frags, 12 stp
    int o = i - OFF_FF2, l = o / 36864, r0 = o % 36864;
    int nf = r0 / 6144, r = r0 % 6144, stp = r / 512, q = r & 511;
    int lane = q >> 3, h8i = q & 7, lr = lane & 15, lg = lane >> 4;
    int st = stp * 2 + (h8i >> 2), j = h8i & 3;
    int n = nf * 16 + lr, k = st * 16 + lg * 4 + j;
    v = w_ff2[l * 36864 + k * 96 + n];
  } else {                                 // ACT: 1 frag, 3 stp
    int o = i - OFF_ACT, stp = o / 512, q = o & 511;
    int lane = q >> 3, h8i = q & 7, lr = lane & 15, lg = lane >> 4;
    int st = stp * 2 + (h8i >> 2), j = h8i & 3;
    int k = st * 16 + lg * 4 + j;
    v = w_act[k * 16 + lr];
  }
  P[i] = (_Float16)v;
}

// Shared mapping: block (b=blk>>4, jj=blk&15) owns batch-b chunks
// m = {2jj, 2jj+1, 62-2jj, 63-2jj} (mirrored for causal attn balance).
// x residual slots: [(blk*4+g)*6+cf][lane][4] fp32 (slot-addressed).
// QKV paired tiles: [bh][tile32][lane][8]; chunk g -> tile (g<2?jj:31-jj), half g&1.

// ---------- embed kernel: concat+embed+pos -> x; LN1+qkv -> QKV[0] ----------
__global__ __launch_bounds__(384, 1) void embed_kernel(
    const float* __restrict__ goals, const float* __restrict__ obss,
    const float* __restrict__ pos, const float* __restrict__ b_go,
    const _Float16* __restrict__ Wp, float* __restrict__ x,
    const float* __restrict__ lntg, const float* __restrict__ lntb,
    const _Float16* __restrict__ Wtail,
    _Float16* __restrict__ qp_, _Float16* __restrict__ kp_,
    _Float16* __restrict__ vp_) {
  __shared__ float smemf[16128];
#define XSH(g, row, c) ((_Float16*)smemf + (size_t)(g) * 1920 + (row) * 20 + (c))
#define LNS(g, w, r, i) smemf[15360 + (((g) * 6 + (w)) * 16 + (r)) * 2 + (i)]
#define XP(g) (x + ((size_t)(blockIdx.x * 4 + (g)) * 6 + cfo) * 256 + lane * 4)
  const int tid = threadIdx.x;
  const int wave = tid >> 6, lane = tid & 63;
  const int lr = lane & 15, lg = lane >> 4;
  const int b = blockIdx.x >> 4, jj = blockIdx.x & 15;
  const int cfo = wave;
  const f4 zero4 = {0.f, 0.f, 0.f, 0.f};
  int mrow[4] = {2 * jj, 2 * jj + 1, 62 - 2 * jj, 63 - 2 * jj};
  int tt_[4], t2_[4];
#pragma unroll
  for (int g = 0; g < 4; ++g) { tt_[g] = mrow[g] * 16 + lr; t2_[g] = (g < 2) ? jj : 31 - jj; }

  f4 xc[4];
  h4 ef[4][6];
#pragma unroll
  for (int st = 0; st < 2; ++st) {
    f4 s4 = *(const f4*)(goals + b * 32 + st * 16 + lg * 4);
    h4 e = (h4){(_Float16)s4[0], (_Float16)s4[1], (_Float16)s4[2], (_Float16)s4[3]};
#pragma unroll
    for (int g = 0; g < 4; ++g) ef[g][st] = e;
  }
#pragma unroll
  for (int g = 0; g < 4; ++g)
#pragma unroll
    for (int st = 2; st < 6; ++st) {
      f4 s4 = *(const f4*)(obss + (size_t)(b * 1024 + tt_[g]) * 64 +
                           (st - 2) * 16 + lg * 4);
      ef[g][st] = (h4){(_Float16)s4[0], (_Float16)s4[1], (_Float16)s4[2], (_Float16)s4[3]};
    }
  h4 wf[6];
#pragma unroll
  for (int stp = 0; stp < 3; ++stp)
    ldpair(Wp, cfo * 3 + stp, lane, wf[2 * stp], wf[2 * stp + 1]);
  f4 bb = *(const f4*)(b_go + cfo * 16 + lg * 4);
#pragma unroll
  for (int g = 0; g < 4; ++g) {
    f4 a = zero4;
#pragma unroll
    for (int st = 0; st < 6; ++st) a = MFMA16(wf[st], ef[g][st], a, 0, 0, 0);
    f4 pp = *(const f4*)(pos + (size_t)tt_[g] * 96 + cfo * 16 + lg * 4);
#pragma unroll
    for (int j = 0; j < 4; ++j) xc[g][j] = a[j] + bb[j] + pp[j];
    *(f4*)XP(g) = xc[g];
  }

  // LN1 + qkv tail
#pragma unroll
  for (int g = 0; g < 4; ++g) {
    float s = xc[g][0] + xc[g][1] + xc[g][2] + xc[g][3];
    float sq = xc[g][0] * xc[g][0] + xc[g][1] * xc[g][1] +
               xc[g][2] * xc[g][2] + xc[g][3] * xc[g][3];
    s += __shfl_xor(s, 16); sq += __shfl_xor(sq, 16);
    s += __shfl_xor(s, 32); sq += __shfl_xor(sq, 32);
    if (lane < 16) { LNS(g, wave, lr, 0) = s; LNS(g, wave, lr, 1) = sq; }
  }
  __syncthreads();
  {
    f4 gg4 = *(const f4*)(lntg + cfo * 16 + lg * 4);
    f4 b4 = *(const f4*)(lntb + cfo * 16 + lg * 4);
#pragma unroll
    for (int g = 0; g < 4; ++g) {
      float s = 0.f, sq = 0.f;
#pragma unroll
      for (int w = 0; w < 6; ++w) { s += LNS(g, w, lr, 0); sq += LNS(g, w, lr, 1); }
      float mean = s * (1.f / 96.f);
      float rs = rsqrtf(sq * (1.f / 96.f) - mean * mean + 1e-5f);
      h4 xn;
#pragma unroll
      for (int j = 0; j < 4; ++j)
        xn[j] = (_Float16)((xc[g][j] - mean) * rs * gg4[j] + b4[j]);
      *(h4*)XSH(g, cfo * 16 + lr, lg * 4) = xn;
    }
  }
  __syncthreads();
  h4 xf[4][6];
#pragma unroll
  for (int g = 0; g < 4; ++g)
#pragma unroll
    for (int st = 0; st < 6; ++st)
      xf[g][st] = *(const h4*)XSH(g, st * 16 + lr, lg * 4);
#pragma unroll
  for (int f = 0; f < 3; ++f) {
    int nf = wave * 3 + f;
    h4 wt[6];
#pragma unroll
    for (int stp = 0; stp < 3; ++stp)
      ldpair(Wtail, nf * 3 + stp, lane, wt[2 * stp], wt[2 * stp + 1]);
#pragma unroll
    for (int g = 0; g < 4; ++g) {
      f4 a = zero4;
#pragma unroll
      for (int st = 0; st < 6; ++st) a = MFMA16(wt[st], xf[g][st], a, 0, 0, 0);
      if (nf < 12) {
        int h = nf < 6 ? nf : nf - 6;
        _Float16* dst = (nf < 6 ? qp_ : kp_) +
                        ((size_t)(b * NH_ + h) * 32 + t2_[g]) * 512 +
                        lane * 8 + (g & 1) * 4;
        h4 hv = {(_Float16)a[0], (_Float16)a[1], (_Float16)a[2], (_Float16)a[3]};
        *(h4*)dst = hv;
      } else {
        int hb = nf - 12;
        _Float16* vbase = vp_ + ((size_t)(b * NH_ + hb) * 32 + t2_[g]) * 512;
        int jb = (lr & 3) + (g & 1) * 4;
        int lgp = lr >> 2;
#pragma unroll
        for (int r = 0; r < 4; ++r)
          vbase[(lgp * 16 + lg * 4 + r) * 8 + jb] = (_Float16)a[r];
      }
    }
  }
#undef XSH
#undef LNS
#undef XP
}

// ---------- fused layer kernel: attn (LDS out) + proj + MLP + (qkv|head) ----
// attn: wave = head; dual q-blocks qA=jj (chunks 0,1), qB=31-jj (chunks 2,3)
// share one K/V tile stream (1 tile load -> 4 q-subtiles).
template <bool HEAD>
__global__ __launch_bounds__(384, 1) void layer_kernel(
    const _Float16* __restrict__ Qs, const _Float16* __restrict__ Ks,
    const _Float16* __restrict__ Vs,
    const _Float16* __restrict__ Wp, const float* __restrict__ bp,
    float* __restrict__ x,
    const _Float16* __restrict__ W1, const float* __restrict__ b1,
    const _Float16* __restrict__ W2, const float* __restrict__ b2,
    const float* __restrict__ ln2g, const float* __restrict__ ln2b,
    const float* __restrict__ lntg, const float* __restrict__ lntb,
    const _Float16* __restrict__ Wtail, const float* __restrict__ btail,
    _Float16* __restrict__ qp_, _Float16* __restrict__ kp_,
    _Float16* __restrict__ vp_, float* __restrict__ out) {
  __shared__ float smemf[16128];  // 64512 B
#define XSH(g, row, c) ((_Float16*)smemf + (size_t)(g) * 1920 + (row) * 20 + (c))
#define OSH ((_Float16*)smemf + 7680)
#define HSP(g, fp) ((_Float16*)smemf + ((size_t)(g) * 12 + (fp)) * 512)
#define LNS(g, w, r, i) smemf[15360 + (((g) * 6 + (w)) * 16 + (r)) * 2 + (i)]
#define XP(g) (x + ((size_t)(blockIdx.x * 4 + (g)) * 6 + cfo) * 256 + lane * 4)
  const int tid = threadIdx.x;
  const int wave = tid >> 6, lane = tid & 63;
  const int lr = lane & 15, lg = lane >> 4;
  const int b = blockIdx.x >> 4, jj = blockIdx.x & 15;
  const int cfo = wave;
  const f4 zero4 = {0.f, 0.f, 0.f, 0.f};
  const h4 ones = {(_Float16)1.f, (_Float16)1.f, (_Float16)1.f, (_Float16)1.f};
  int mrow[4] = {2 * jj, 2 * jj + 1, 62 - 2 * jj, 63 - 2 * jj};
  int tt_[4], tok_[4], t2_[4];
#pragma unroll
  for (int g = 0; g < 4; ++g) {
    tt_[g] = mrow[g] * 16 + lr;
    tok_[g] = b * 1024 + tt_[g];
    t2_[g] = (g < 2) ? jj : 31 - jj;
  }

  // ================= attention phase =================
  {
    const size_t bhoff = (size_t)(b * NH_ + wave) * 16384;
    const _Float16* qB_ = Qs + bhoff;
    const _Float16* kB_ = Ks + bhoff;
    const _Float16* vB_ = Vs + bhoff;
    const int qA = jj, qB2 = 31 - jj;  // qA < qB2 always (jj in 0..15)
    h4 qfA0, qfA1, qfB0, qfB1;
    {
      h8 t = *(const h8*)(qB_ + (size_t)qA * 512 + lane * 8);
      qfA0 = __builtin_shufflevector(t, t, 0, 1, 2, 3);
      qfA1 = __builtin_shufflevector(t, t, 4, 5, 6, 7);
      h8 t2v = *(const h8*)(qB_ + (size_t)qB2 * 512 + lane * 8);
      qfB0 = __builtin_shufflevector(t2v, t2v, 0, 1, 2, 3);
      qfB1 = __builtin_shufflevector(t2v, t2v, 4, 5, 6, 7);
    }
    f4 OA0 = zero4, OA1 = zero4, SA0 = zero4, SA1 = zero4;
    f4 OB0 = zero4, OB1 = zero4, SB0 = zero4, SB1 = zero4;
    h4 kc0, kc1, vc0, vc1, kn0, kn1, vn0, vn1;
    ldkv(kB_, vB_, 0, lane, kc0, kc1, vc0, vc1);
    for (int t3 = 0; t3 < qA; ++t3) {
      ldkv(kB_, vB_, t3 + 1, lane, kn0, kn1, vn0, vn1);
      astep_full(kc0, kc1, vc0, vc1, qfA0, qfA1, ones, OA0, OA1, SA0, SA1);
      astep_full(kc0, kc1, vc0, vc1, qfB0, qfB1, ones, OB0, OB1, SB0, SB1);
      kc0 = kn0; kc1 = kn1; vc0 = vn0; vc1 = vn1;
    }
    // tile qA: A diag + B full; prefetch qA+1 (always <= qB2 <= 31)
    {
      ldkv(kB_, vB_, qA + 1, lane, kn0, kn1, vn0, vn1);
      astep_diag(kc0, kc1, vc0, vc1, qfA0, qfA1, ones, OA0, OA1, SA0, SA1, lr, lg);
      astep_full(kc0, kc1, vc0, vc1, qfB0, qfB1, ones, OB0, OB1, SB0, SB1);
      kc0 = kn0; kc1 = kn1; vc0 = vn0; vc1 = vn1;
    }
    for (int t3 = qA + 1; t3 < qB2; ++t3) {
      ldkv(kB_, vB_, t3 + 1, lane, kn0, kn1, vn0, vn1);
      astep_full(kc0, kc1, vc0, vc1, qfB0, qfB1, ones, OB0, OB1, SB0, SB1);
      kc0 = kn0; kc1 = kn1; vc0 = vn0; vc1 = vn1;
    }
    astep_diag(kc0, kc1, vc0, vc1, qfB0, qfB1, ones, OB0, OB1, SB0, SB1, lr, lg);
    // write OSH (chunk g, stp = head>>1, half = head&1)
    int stp = wave >> 1;
    int jb = (lr & 3) + (wave & 1) * 4;
    int lgp = lr >> 2;
#pragma unroll
    for (int r = 0; r < 4; ++r) {
      int pos = (lgp * 16 + lg * 4 + r) * 8 + jb;
      OSH[(0 * 3 + stp) * 512 + pos] = (_Float16)(OA0[r] * __builtin_amdgcn_rcpf(SA0[r]));
      OSH[(1 * 3 + stp) * 512 + pos] = (_Float16)(OA1[r] * __builtin_amdgcn_rcpf(SA1[r]));
      OSH[(2 * 3 + stp) * 512 + pos] = (_Float16)(OB0[r] * __builtin_amdgcn_rcpf(SB0[r]));
      OSH[(3 * 3 + stp) * 512 + pos] = (_Float16)(OB1[r] * __builtin_amdgcn_rcpf(SB1[r]));
    }
  }
  __syncthreads();  // A-bar: OSH complete

  // ================= stage =================
  f4 xc[4], x1[4];
  // ---- proj + resid: obf from OSH ----
  h4 obf[4][6];
#pragma unroll
  for (int g = 0; g < 4; ++g)
#pragma unroll
    for (int stp = 0; stp < 3; ++stp) {
      h8 t = *(const h8*)(OSH + ((size_t)(g * 3 + stp)) * 512 + lane * 8);
      obf[g][2 * stp] = __builtin_shufflevector(t, t, 0, 1, 2, 3);
      obf[g][2 * stp + 1] = __builtin_shufflevector(t, t, 4, 5, 6, 7);
    }
  h4 wf[6];
#pragma unroll
  for (int stp = 0; stp < 3; ++stp)
    ldpair(Wp, cfo * 3 + stp, lane, wf[2 * stp], wf[2 * stp + 1]);
  f4 bb = *(const f4*)(bp + cfo * 16 + lg * 4);
#pragma unroll
  for (int g = 0; g < 4; ++g) {
    f4 a = zero4;
#pragma unroll
    for (int st = 0; st < 6; ++st) a = MFMA16(wf[st], obf[g][st], a, 0, 0, 0);
    f4 xr = *(const f4*)XP(g);
#pragma unroll
    for (int j = 0; j < 4; ++j) x1[g][j] = a[j] + bb[j] + xr[j];
  }
  // ---- LN2 ----
#pragma unroll
  for (int g = 0; g < 4; ++g) {
    float s = x1[g][0] + x1[g][1] + x1[g][2] + x1[g][3];
    float sq = x1[g][0] * x1[g][0] + x1[g][1] * x1[g][1] +
               x1[g][2] * x1[g][2] + x1[g][3] * x1[g][3];
    s += __shfl_xor(s, 16); sq += __shfl_xor(sq, 16);
    s += __shfl_xor(s, 32); sq += __shfl_xor(sq, 32);
    if (lane < 16) { LNS(g, wave, lr, 0) = s; LNS(g, wave, lr, 1) = sq; }
  }
  __syncthreads();  // B1
  {
    f4 gg4 = *(const f4*)(ln2g + cfo * 16 + lg * 4);
    f4 b4 = *(const f4*)(ln2b + cfo * 16 + lg * 4);
#pragma unroll
    for (int g = 0; g < 4; ++g) {
      float s = 0.f, sq = 0.f;
#pragma unroll
      for (int w = 0; w < 6; ++w) { s += LNS(g, w, lr, 0); sq += LNS(g, w, lr, 1); }
      float mean = s * (1.f / 96.f);
      float rs = rsqrtf(sq * (1.f / 96.f) - mean * mean + 1e-5f);
      h4 xn;
#pragma unroll
      for (int j = 0; j < 4; ++j)
        xn[j] = (_Float16)((x1[g][j] - mean) * rs * gg4[j] + b4[j]);
      *(h4*)XSH(g, cfo * 16 + lr, lg * 4) = xn;
    }
  }
  __syncthreads();  // B2
  h4 xnf[4][6];
#pragma unroll
  for (int g = 0; g < 4; ++g)
#pragma unroll
    for (int st = 0; st < 6; ++st)
      xnf[g][st] = *(const h4*)XSH(g, st * 16 + lr, lg * 4);
  __syncthreads();  // B2b: XSH/OSH dead, HSP may overlay

  // ---- ff1 + relu -> HSP pairs ----
#pragma unroll
  for (int p = 0; p < 2; ++p) {
    int nf0 = wave * 4 + p * 2;
    h4 wA[6], wB[6];
#pragma unroll
    for (int stp = 0; stp < 3; ++stp) {
      ldpair(W1, nf0 * 3 + stp, lane, wA[2 * stp], wA[2 * stp + 1]);
      ldpair(W1, (nf0 + 1) * 3 + stp, lane, wB[2 * stp], wB[2 * stp + 1]);
    }
    f4 bA = *(const f4*)(b1 + nf0 * 16 + lg * 4);
    f4 bB = *(const f4*)(b1 + (nf0 + 1) * 16 + lg * 4);
#pragma unroll
    for (int g = 0; g < 4; ++g) {
      f4 hA = zero4, hB = zero4;
#pragma unroll
      for (int st = 0; st < 6; ++st) {
        hA = MFMA16(wA[st], xnf[g][st], hA, 0, 0, 0);
        hB = MFMA16(wB[st], xnf[g][st], hB, 0, 0, 0);
      }
      h4 lo, hi;
#pragma unroll
      for (int j = 0; j < 4; ++j) {
        lo[j] = (_Float16)fmaxf(hA[j] + bA[j], 0.f);
        hi[j] = (_Float16)fmaxf(hB[j] + bB[j], 0.f);
      }
      h8 comb = __builtin_shufflevector(lo, hi, 0, 1, 2, 3, 4, 5, 6, 7);
      *(h8*)(HSP(g, wave * 2 + p) + lane * 8) = comb;
    }
  }
  // ---- ff2 ----
  h4 w2f[24];
#pragma unroll
  for (int stp = 0; stp < 12; ++stp)
    ldpair(W2, cfo * 12 + stp, lane, w2f[2 * stp], w2f[2 * stp + 1]);
  __syncthreads();  // B3
  {
    f4 b4 = *(const f4*)(b2 + cfo * 16 + lg * 4);
#pragma unroll
    for (int g = 0; g < 4; ++g) {
      f4 y = zero4;
#pragma unroll
      for (int fp = 0; fp < 12; ++fp) {
        h8 t = *(const h8*)(HSP(g, fp) + lane * 8);
        h4 lo = __builtin_shufflevector(t, t, 0, 1, 2, 3);
        h4 hi = __builtin_shufflevector(t, t, 4, 5, 6, 7);
        y = MFMA16(w2f[2 * fp], lo, y, 0, 0, 0);
        y = MFMA16(w2f[2 * fp + 1], hi, y, 0, 0, 0);
      }
#pragma unroll
      for (int j = 0; j < 4; ++j) xc[g][j] = x1[g][j] + y[j] + b4[j];
      if constexpr (!HEAD)
        *(f4*)XP(g) = xc[g];
    }
  }

  // ---- tail LN on xc ----
#pragma unroll
  for (int g = 0; g < 4; ++g) {
    float s = xc[g][0] + xc[g][1] + xc[g][2] + xc[g][3];
    float sq = xc[g][0] * xc[g][0] + xc[g][1] * xc[g][1] +
               xc[g][2] * xc[g][2] + xc[g][3] * xc[g][3];
    s += __shfl_xor(s, 16); sq += __shfl_xor(sq, 16);
    s += __shfl_xor(s, 32); sq += __shfl_xor(sq, 32);
    if (lane < 16) { LNS(g, wave, lr, 0) = s; LNS(g, wave, lr, 1) = sq; }
  }
  __syncthreads();  // B4
  {
    f4 gg4 = *(const f4*)(lntg + cfo * 16 + lg * 4);
    f4 b4 = *(const f4*)(lntb + cfo * 16 + lg * 4);
#pragma unroll
    for (int g = 0; g < 4; ++g) {
      float s = 0.f, sq = 0.f;
#pragma unroll
      for (int w = 0; w < 6; ++w) { s += LNS(g, w, lr, 0); sq += LNS(g, w, lr, 1); }
      float mean = s * (1.f / 96.f);
      float rs = rsqrtf(sq * (1.f / 96.f) - mean * mean + 1e-5f);
      h4 xn;
#pragma unroll
      for (int j = 0; j < 4; ++j)
        xn[j] = (_Float16)((xc[g][j] - mean) * rs * gg4[j] + b4[j]);
      *(h4*)XSH(g, cfo * 16 + lr, lg * 4) = xn;
    }
  }
  __syncthreads();  // B5
  if constexpr (HEAD) {
    if (wave == 0) {
      h4 wt[6];
#pragma unroll
      for (int stp = 0; stp < 3; ++stp)
        ldpair(Wtail, stp, lane, wt[2 * stp], wt[2 * stp + 1]);
      f4 bbt = *(const f4*)(btail + lg * 4);
#pragma unroll
      for (int g = 0; g < 4; ++g) {
        f4 a = zero4;
#pragma unroll
        for (int st = 0; st < 6; ++st) {
          h4 xf = *(const h4*)XSH(g, st * 16 + lr, lg * 4);
          a = MFMA16(wt[st], xf, a, 0, 0, 0);
        }
        f4 o;
#pragma unroll
        for (int j = 0; j < 4; ++j) o[j] = a[j] + bbt[j];
        *(f4*)(out + (size_t)tok_[g] * 16 + lg * 4) = o;
      }
    }
  } else {
    h4 xf[4][6];
#pragma unroll
    for (int g = 0; g < 4; ++g)
#pragma unroll
      for (int st = 0; st < 6; ++st)
        xf[g][st] = *(const h4*)XSH(g, st * 16 + lr, lg * 4);
#pragma unroll
    for (int f = 0; f < 3; ++f) {
      int nf = wave * 3 + f;
      h4 wt[6];
#pragma unroll
      for (int stp = 0; stp < 3; ++stp)
        ldpair(Wtail, nf * 3 + stp, lane, wt[2 * stp], wt[2 * stp + 1]);
#pragma unroll
      for (int g = 0; g < 4; ++g) {
        f4 a = zero4;
#pragma unroll
        for (int st = 0; st < 6; ++st) a = MFMA16(wt[st], xf[g][st], a, 0, 0, 0);
        if (nf < 12) {
          int h = nf < 6 ? nf : nf - 6;
          _Float16* dst = (nf < 6 ? qp_ : kp_) +
                          ((size_t)(b * NH_ + h) * 32 + t2_[g]) * 512 +
                          lane * 8 + (g & 1) * 4;
          h4 hv = {(_Float16)a[0], (_Float16)a[1], (_Float16)a[2], (_Float16)a[3]};
          *(h4*)dst = hv;
        } else {
          int hb = nf - 12;
          _Float16* vbase = vp_ + ((size_t)(b * NH_ + hb) * 32 + t2_[g]) * 512;
          int jb = (lr & 3) + (g & 1) * 4;
          int lgp = lr >> 2;
#pragma unroll
          for (int r = 0; r < 4; ++r)
            vbase[(lgp * 16 + lg * 4 + r) * 8 + jb] = (_Float16)a[r];
        }
      }
    }
  }
#undef XSH
#undef OSH
#undef HSP
#undef LNS
#undef XP
}

extern "C" void kernel_launch(void* const* d_in, const int* in_sizes, int n_in,
                              void* d_out, int out_size, void* d_ws, size_t ws_size,
                              hipStream_t stream) {
  const float* goals   = (const float*)d_in[0];
  const float* obss    = (const float*)d_in[1];
  const float* w_go    = (const float*)d_in[2];
  const float* b_go    = (const float*)d_in[3];
  const float* pos_emb = (const float*)d_in[4];
  const float* wq      = (const float*)d_in[5];
  const float* wk      = (const float*)d_in[6];
  const float* wv      = (const float*)d_in[7];
  const float* w_proj  = (const float*)d_in[8];
  const float* b_proj  = (const float*)d_in[9];
  const float* ln1_g   = (const float*)d_in[10];
  const float* ln1_b   = (const float*)d_in[11];
  const float* ln2_g   = (const float*)d_in[12];
  const float* ln2_b   = (const float*)d_in[13];
  const float* w_ff1   = (const float*)d_in[14];
  const float* b_ff1   = (const float*)d_in[15];
  const float* w_ff2   = (const float*)d_in[16];
  const float* b_ff2   = (const float*)d_in[17];
  const float* lnf_g   = (const float*)d_in[18];
  const float* lnf_b   = (const float*)d_in[19];
  const float* w_act   = (const float*)d_in[20];
  const float* b_act   = (const float*)d_in[21];
  float* out = (float*)d_out;

  const int M = B_ * T_;  // 16384
  float* ws = (float*)d_ws;
  size_t off = 0;
  _Float16* P = (_Float16*)(ws + off); off += PACK_TOTAL / 2 + 64;
  float* x = ws + off; off += (size_t)M * 96;
  _Float16* Qb[2]; _Float16* Kb[2]; _Float16* Vb[2];
  for (int p = 0; p < 2; ++p) {
    Qb[p] = (_Float16*)(ws + off); off += (size_t)M * 48;
    Kb[p] = (_Float16*)(ws + off); off += (size_t)M * 48;
    Vb[p] = (_Float16*)(ws + off); off += (size_t)M * 48;
  }

  pack_all_kernel<<<(PACK_TOTAL + 255) / 256, 256, 0, stream>>>(
      w_go, wq, wk, wv, w_proj, w_ff1, w_ff2, w_act, P);

  embed_kernel<<<256, 384, 0, stream>>>(
      goals, obss, pos_emb, b_go, P + OFF_GO, x, ln1_g, ln1_b,
      P + OFF_QKV, Qb[0], Kb[0], Vb[0]);

  for (int l = 0; l < L_; ++l) {
    int sp = l & 1, dp = (l + 1) & 1;
    if (l < L_ - 1) {
      layer_kernel<false><<<256, 384, 0, stream>>>(
          Qb[sp], Kb[sp], Vb[sp],
          P + OFF_PROJ + (size_t)l * 9216, b_proj + l * 96, x,
          P + OFF_FF1 + (size_t)l * 36864, b_ff1 + l * 384,
          P + OFF_FF2 + (size_t)l * 36864, b_ff2 + l * 96,
          ln2_g + l * 96, ln2_b + l * 96,
          ln1_g + (l + 1) * 96, ln1_b + (l + 1) * 96,
          P + OFF_QKV + (size_t)(l + 1) * 27648, nullptr,
          Qb[dp], Kb[dp], Vb[dp], nullptr);
    } else {
      layer_kernel<true><<<256, 384, 0, stream>>>(
          Qb[sp], Kb[sp], Vb[sp],
          P + OFF_PROJ + (size_t)l * 9216, b_proj + l * 96, x,
          P + OFF_FF1 + (size_t)l * 36864, b_ff1 + l * 384,
          P + OFF_FF2 + (size_t)l * 36864, b_ff2 + l * 96,
          ln2_g + l * 96, ln2_b + l * 96,
          lnf_g, lnf_b, P + OFF_ACT, b_act,
          nullptr, nullptr, nullptr, out);
    }
  }
}